// Round 1
// baseline (1563.136 us; speedup 1.0000x reference)
//
#include <hip/hip_runtime.h>
#include <math.h>

#define MAXN 0.996f
#define MINN 1e-15f

__device__ __forceinline__ float wsum(float v){
  v += __shfl_xor(v, 32);
  v += __shfl_xor(v, 16);
  v += __shfl_xor(v, 8);
  v += __shfl_xor(v, 4);
  v += __shfl_xor(v, 2);
  v += __shfl_xor(v, 1);
  return v;
}

__device__ __forceinline__ float artanh_(float v){
  v = fminf(fmaxf(v, -1.f + 1e-7f), 1.f - 1e-7f);
  return 0.5f * (log1pf(v) - log1pf(-v));
}

// Stage A: ht = logmap0(proj(mobius_add(proj(mobius_matvec(W,x)), hyp_bias)))
// One wave handles 4 rows at a time (register-batched to amortize LDS W reads).
__global__ __launch_bounds__(256, 2)
void stageA_kernel(const float* __restrict__ x, const float* __restrict__ W,
                   const float* __restrict__ bias, float* __restrict__ ht, int n)
{
  // W in LDS, XOR-quad swizzled: element (j,k) at (j<<7) + (((k/4) ^ (j&31))<<2) + (k&3)
  // so the per-lane b128 reads (stride 512B) spread across all 32 banks.
  __shared__ float Wsh[128 * 128];
  for(int t = threadIdx.x; t < 128 * 128; t += 256){
    int j = t >> 7, k = t & 127;
    int q = k >> 2, b = k & 3;
    Wsh[(j << 7) + (((q ^ (j & 31)) << 2) | b)] = W[t];
  }
  __syncthreads();

  const int lane = threadIdx.x & 63;
  const int wid  = threadIdx.x >> 6;
  const int j0 = lane, j1 = lane + 64;
  const int sw = lane & 31;

  // hyp_bias = proj(expmap0(bias)); y2 = ||hyp_bias||^2  (per-wave redundant, tiny)
  float b0 = bias[j0], b1 = bias[j1];
  float bn2 = wsum(b0*b0 + b1*b1);
  float bn  = fmaxf(sqrtf(bn2), MINN);
  float sb  = tanhf(bn) / bn;
  float hb0 = sb*b0, hb1 = sb*b1;
  float hn2 = wsum(hb0*hb0 + hb1*hb1);
  float hnn = fmaxf(sqrtf(hn2), MINN);
  if(hnn > MAXN){ float f = MAXN/hnn; hb0 *= f; hb1 *= f; }
  float y2 = wsum(hb0*hb0 + hb1*hb1);

  const int nwaves = gridDim.x << 2;
  for(int base = (blockIdx.x*4 + wid)*4; base < n; base += nwaves*4){
    // per-row ||x||^2
    float x2[4];
#pragma unroll
    for(int r = 0; r < 4; r++){
      const float* xr = x + (size_t)(base + r) * 128;
      float a = xr[j0], c = xr[j1];
      x2[r] = wsum(a*a + c*c);
    }
    // mx = x @ W^T : lane owns output dims j0,j1 for 4 rows
    float acc[4][2] = {{0.f,0.f},{0.f,0.f},{0.f,0.f},{0.f,0.f}};
    for(int kq = 0; kq < 32; kq++){
      float4 wa = *(const float4*)&Wsh[(j0 << 7) + ((kq ^ sw) << 2)];
      float4 wb = *(const float4*)&Wsh[(j1 << 7) + ((kq ^ sw) << 2)];
#pragma unroll
      for(int r = 0; r < 4; r++){
        float4 xv = *(const float4*)(x + (size_t)(base + r) * 128 + kq * 4); // wave-uniform broadcast
        acc[r][0] = fmaf(xv.w, wa.w, fmaf(xv.z, wa.z, fmaf(xv.y, wa.y, fmaf(xv.x, wa.x, acc[r][0]))));
        acc[r][1] = fmaf(xv.w, wb.w, fmaf(xv.z, wb.z, fmaf(xv.y, wb.y, fmaf(xv.x, wb.x, acc[r][1]))));
      }
    }
#pragma unroll
    for(int r = 0; r < 4; r++){
      float m0 = acc[r][0], m1 = acc[r][1];
      float mx2 = wsum(m0*m0 + m1*m1);
      float mxn = fmaxf(sqrtf(mx2), MINN);
      float xn  = fmaxf(sqrtf(x2[r]), MINN);
      // mobius_matvec tail: res = tanh(mxn/xn * artanh(xn)) * mx / mxn
      float t   = tanhf(mxn / xn * artanh_(xn));
      float s1  = t / mxn;
      // proj(res): ||res|| == t analytically
      float rn  = fmaxf(t, MINN);
      if(rn > MAXN) s1 *= MAXN / rn;
      float r0 = s1*m0, r1 = s1*m1;
      float x2r = s1*s1*mx2;
      // mobius_add(res, hyp_bias)
      float xy    = wsum(r0*hb0 + r1*hb1);
      float alpha = 1.f + 2.f*xy + y2;
      float beta  = 1.f - x2r;
      float inv   = 1.f / fmaxf(1.f + 2.f*xy + x2r*y2, MINN);
      float u0 = (alpha*r0 + beta*hb0) * inv;
      float u1 = (alpha*r1 + beta*hb1) * inv;
      // proj then logmap0
      float u2 = wsum(u0*u0 + u1*u1);
      float un = fmaxf(sqrtf(u2), MINN);
      float sc = 1.f, hn = un;
      if(un > MAXN){ sc = MAXN/un; hn = MAXN; }
      float lt = artanh_(hn) / hn * sc;
      float* hr = ht + (size_t)(base + r) * 128;
      hr[j0] = lt*u0;
      hr[j1] = lt*u1;
    }
  }
}

// Stage B: agg[r] += w[e] * ht[s]  (32 threads x float4 per edge, native f32 atomics)
__global__ __launch_bounds__(256)
void edge_kernel(const int* __restrict__ adj, const float* __restrict__ w,
                 const float* __restrict__ ht, float* __restrict__ agg, int E)
{
  int idx = blockIdx.x * 256 + threadIdx.x;
  int e = idx >> 5;
  if(e >= E) return;
  int c = (idx & 31) << 2;
  int s = adj[e];
  int r = adj[e + E];
  float we = w[e];
  float4 v = *(const float4*)(ht + (size_t)s * 128 + c);
  float* dst = agg + (size_t)r * 128 + c;
  unsafeAtomicAdd(dst + 0, v.x * we);
  unsafeAtomicAdd(dst + 1, v.y * we);
  unsafeAtomicAdd(dst + 2, v.z * we);
  unsafeAtomicAdd(dst + 3, v.w * we);
}

// Stage C: out = proj(expmap0(relu(logmap0(proj(expmap0(agg))))))  — one wave per row
__global__ __launch_bounds__(256)
void stageC_kernel(const float* __restrict__ agg, float* __restrict__ out, int n)
{
  int row = blockIdx.x * 4 + (threadIdx.x >> 6);
  if(row >= n) return;
  int lane = threadIdx.x & 63;
  const float* ur = agg + (size_t)row * 128;
  float u0 = ur[lane], u1 = ur[lane + 64];
  float u2 = wsum(u0*u0 + u1*u1);
  float un = fmaxf(sqrtf(u2), MINN);
  float te = tanhf(un);
  float se = te / un;                   // expmap0 scale
  float gn = fmaxf(te, MINN);           // ||expmap0(u)|| analytically
  float hn = gn;
  if(gn > MAXN){ se *= MAXN/gn; hn = MAXN; }
  float la = artanh_(hn) / hn * se;     // logmap0 of h = se*u
  float l0 = fmaxf(la*u0, 0.f), l1 = fmaxf(la*u1, 0.f);  // relu
  float r2 = wsum(l0*l0 + l1*l1);
  float rn = fmaxf(sqrtf(r2), MINN);
  float t2 = tanhf(rn);
  float s2 = t2 / rn;
  float on = fmaxf(t2, MINN);
  if(on > MAXN) s2 *= MAXN/on;
  float* orow = out + (size_t)row * 128;
  orow[lane]      = s2*l0;
  orow[lane + 64] = s2*l1;
}

__global__ __launch_bounds__(256)
void adj_copy_kernel(const int* __restrict__ adj, float* __restrict__ o, int m)
{
  int i = blockIdx.x * 256 + threadIdx.x;
  if(i < m) o[i] = (float)adj[i];
}

extern "C" void kernel_launch(void* const* d_in, const int* in_sizes, int n_in,
                              void* d_out, int out_size, void* d_ws, size_t ws_size,
                              hipStream_t stream)
{
  const float* x    = (const float*)d_in[0];
  const int*   adj  = (const int*)  d_in[1];
  const float* w    = (const float*)d_in[2];
  const float* W    = (const float*)d_in[3];
  const float* bias = (const float*)d_in[4];
  const int n = in_sizes[0] / 128;   // 50000
  const int E = in_sizes[2];         // 800000

  float* out     = (float*)d_out;
  float* ht      = out;              // [n*128] — consumed by edge_kernel before stageC overwrites
  float* agg     = (float*)d_ws;     // [n*128]
  float* adj_out = out + (size_t)n * 128;

  hipMemsetAsync(agg, 0, (size_t)n * 128 * sizeof(float), stream);
  stageA_kernel<<<512, 256, 0, stream>>>(x, W, bias, ht, n);
  edge_kernel<<<(E * 32 + 255) / 256, 256, 0, stream>>>(adj, w, ht, agg, E);
  stageC_kernel<<<(n + 3) / 4, 256, 0, stream>>>(agg, out, n);
  adj_copy_kernel<<<(2 * E + 255) / 256, 256, 0, stream>>>(adj, adj_out, 2 * E);
}

// Round 2
// 353.656 us; speedup vs baseline: 4.4199x; 4.4199x over previous
//
#include <hip/hip_runtime.h>
#include <math.h>

#define MAXN 0.996f
#define MINN 1e-15f

__device__ __forceinline__ float wsum(float v){
  v += __shfl_xor(v, 32);
  v += __shfl_xor(v, 16);
  v += __shfl_xor(v, 8);
  v += __shfl_xor(v, 4);
  v += __shfl_xor(v, 2);
  v += __shfl_xor(v, 1);
  return v;
}

__device__ __forceinline__ float artanh_(float v){
  v = fminf(fmaxf(v, -1.f + 1e-7f), 1.f - 1e-7f);
  return 0.5f * (log1pf(v) - log1pf(-v));
}

// ---------------- Stage A: ht = logmap0(proj(mobius_add(proj(mobius_matvec(W,x)), hyp_bias)))
__global__ __launch_bounds__(256, 2)
void stageA_kernel(const float* __restrict__ x, const float* __restrict__ W,
                   const float* __restrict__ bias, float* __restrict__ ht, int n)
{
  __shared__ float Wsh[128 * 128];
  for(int t = threadIdx.x; t < 128 * 128; t += 256){
    int j = t >> 7, k = t & 127;
    int q = k >> 2, b = k & 3;
    Wsh[(j << 7) + (((q ^ (j & 31)) << 2) | b)] = W[t];
  }
  __syncthreads();

  const int lane = threadIdx.x & 63;
  const int wid  = threadIdx.x >> 6;
  const int j0 = lane, j1 = lane + 64;
  const int sw = lane & 31;

  float b0 = bias[j0], b1 = bias[j1];
  float bn2 = wsum(b0*b0 + b1*b1);
  float bn  = fmaxf(sqrtf(bn2), MINN);
  float sb  = tanhf(bn) / bn;
  float hb0 = sb*b0, hb1 = sb*b1;
  float hn2 = wsum(hb0*hb0 + hb1*hb1);
  float hnn = fmaxf(sqrtf(hn2), MINN);
  if(hnn > MAXN){ float f = MAXN/hnn; hb0 *= f; hb1 *= f; }
  float y2 = wsum(hb0*hb0 + hb1*hb1);

  const int nwaves = gridDim.x << 2;
  for(int base = (blockIdx.x*4 + wid)*4; base < n; base += nwaves*4){
    float x2[4];
#pragma unroll
    for(int r = 0; r < 4; r++){
      const float* xr = x + (size_t)(base + r) * 128;
      float a = xr[j0], c = xr[j1];
      x2[r] = wsum(a*a + c*c);
    }
    float acc[4][2] = {{0.f,0.f},{0.f,0.f},{0.f,0.f},{0.f,0.f}};
    for(int kq = 0; kq < 32; kq++){
      float4 wa = *(const float4*)&Wsh[(j0 << 7) + ((kq ^ sw) << 2)];
      float4 wb = *(const float4*)&Wsh[(j1 << 7) + ((kq ^ sw) << 2)];
#pragma unroll
      for(int r = 0; r < 4; r++){
        float4 xv = *(const float4*)(x + (size_t)(base + r) * 128 + kq * 4);
        acc[r][0] = fmaf(xv.w, wa.w, fmaf(xv.z, wa.z, fmaf(xv.y, wa.y, fmaf(xv.x, wa.x, acc[r][0]))));
        acc[r][1] = fmaf(xv.w, wb.w, fmaf(xv.z, wb.z, fmaf(xv.y, wb.y, fmaf(xv.x, wb.x, acc[r][1]))));
      }
    }
#pragma unroll
    for(int r = 0; r < 4; r++){
      float m0 = acc[r][0], m1 = acc[r][1];
      float mx2 = wsum(m0*m0 + m1*m1);
      float mxn = fmaxf(sqrtf(mx2), MINN);
      float xn  = fmaxf(sqrtf(x2[r]), MINN);
      float t   = tanhf(mxn / xn * artanh_(xn));
      float s1  = t / mxn;
      float rn  = fmaxf(t, MINN);
      if(rn > MAXN) s1 *= MAXN / rn;
      float r0 = s1*m0, r1 = s1*m1;
      float x2r = s1*s1*mx2;
      float xy    = wsum(r0*hb0 + r1*hb1);
      float alpha = 1.f + 2.f*xy + y2;
      float beta  = 1.f - x2r;
      float inv   = 1.f / fmaxf(1.f + 2.f*xy + x2r*y2, MINN);
      float u0 = (alpha*r0 + beta*hb0) * inv;
      float u1 = (alpha*r1 + beta*hb1) * inv;
      float u2 = wsum(u0*u0 + u1*u1);
      float un = fmaxf(sqrtf(u2), MINN);
      float sc = 1.f, hn = un;
      if(un > MAXN){ sc = MAXN/un; hn = MAXN; }
      float lt = artanh_(hn) / hn * sc;
      float* hr = ht + (size_t)(base + r) * 128;
      hr[j0] = lt*u0;
      hr[j1] = lt*u1;
    }
  }
}

// ---------------- CSR build ----------------
__global__ __launch_bounds__(256)
void count_kernel(const int* __restrict__ adj, int* __restrict__ cnt, int E)
{
  int e = blockIdx.x * 256 + threadIdx.x;
  if(e < E) atomicAdd(&cnt[adj[e + E]], 1);
}

// block-local exclusive scan; writes per-element exclusive + per-block total
__global__ __launch_bounds__(256)
void scan1_kernel(const int* __restrict__ cnt, int* __restrict__ offs,
                  int* __restrict__ bsum, int n)
{
  int i = blockIdx.x * 256 + threadIdx.x;
  int lane = threadIdx.x & 63, wid = threadIdx.x >> 6;
  int v = (i < n) ? cnt[i] : 0;
  int iv = v;
#pragma unroll
  for(int o = 1; o < 64; o <<= 1){
    int t = __shfl_up(iv, o);
    if(lane >= o) iv += t;
  }
  __shared__ int wsums[4];
  if(lane == 63) wsums[wid] = iv;
  __syncthreads();
  int wbase = 0;
  for(int k = 0; k < wid; k++) wbase += wsums[k];
  if(i < n) offs[i] = wbase + iv - v;
  if(threadIdx.x == 255) bsum[blockIdx.x] = wbase + iv;
}

// single-block exclusive scan of block sums (nb <= 256); also offs[n] = E
__global__ __launch_bounds__(256)
void scan2_kernel(int* __restrict__ bsum, int* __restrict__ offs, int nb, int n, int E)
{
  int t = threadIdx.x;
  int lane = t & 63, wid = t >> 6;
  int v = (t < nb) ? bsum[t] : 0;
  int iv = v;
#pragma unroll
  for(int o = 1; o < 64; o <<= 1){
    int s = __shfl_up(iv, o);
    if(lane >= o) iv += s;
  }
  __shared__ int wsums[4];
  if(lane == 63) wsums[wid] = iv;
  __syncthreads();
  int wbase = 0;
  for(int k = 0; k < wid; k++) wbase += wsums[k];
  int excl = wbase + iv - v;
  __syncthreads();
  if(t < nb) bsum[t] = excl;
  if(t == 0) offs[n] = E;
}

// add block offsets; init cursor = row start
__global__ __launch_bounds__(256)
void scan3_kernel(int* __restrict__ offs, const int* __restrict__ bsum,
                  int* __restrict__ cursor, int n)
{
  int i = blockIdx.x * 256 + threadIdx.x;
  if(i < n){
    int o = offs[i] + bsum[blockIdx.x];
    offs[i] = o;
    cursor[i] = o;
  }
}

__global__ __launch_bounds__(256)
void scatter_kernel(const int* __restrict__ adj, const float* __restrict__ w,
                    int* __restrict__ cursor, int* __restrict__ sidx,
                    float* __restrict__ wval, int E)
{
  int e = blockIdx.x * 256 + threadIdx.x;
  if(e >= E) return;
  int r = adj[e + E];
  int idx = atomicAdd(&cursor[r], 1);
  sidx[idx] = adj[e];
  wval[idx] = w[e];
}

// ---------------- fused aggregate + HypAct: one wave per destination row ----------------
__global__ __launch_bounds__(256)
void agg_act_kernel(const int* __restrict__ offs, const int* __restrict__ sidx,
                    const float* __restrict__ wval, const float* __restrict__ ht,
                    float* __restrict__ out, int n)
{
  int row = blockIdx.x * 4 + (threadIdx.x >> 6);
  if(row >= n) return;
  int lane = threadIdx.x & 63;
  int beg = offs[row], end = offs[row + 1];

  float a0 = 0.f, a1 = 0.f;
  for(int j = beg; j < end; j += 64){
    int m = end - j; if(m > 64) m = 64;
    int sv = 0; float wv = 0.f;
    if(lane < m){ sv = sidx[j + lane]; wv = wval[j + lane]; }
    for(int t = 0; t < m; t++){
      int s = __shfl(sv, t);
      float we = __shfl(wv, t);
      const float* hr = ht + (size_t)s * 128;
      a0 = fmaf(we, hr[lane], a0);
      a1 = fmaf(we, hr[lane + 64], a1);
    }
  }

  // HypAct: proj(expmap0(relu(logmap0(proj(expmap0(agg))))))
  float u2 = wsum(a0*a0 + a1*a1);
  float un = fmaxf(sqrtf(u2), MINN);
  float te = tanhf(un);
  float se = te / un;
  float gn = fmaxf(te, MINN);
  float hn = gn;
  if(gn > MAXN){ se *= MAXN/gn; hn = MAXN; }
  float la = artanh_(hn) / hn * se;
  float l0 = fmaxf(la*a0, 0.f), l1 = fmaxf(la*a1, 0.f);
  float r2 = wsum(l0*l0 + l1*l1);
  float rn = fmaxf(sqrtf(r2), MINN);
  float t2 = tanhf(rn);
  float s2 = t2 / rn;
  float on = fmaxf(t2, MINN);
  if(on > MAXN) s2 *= MAXN/on;
  float* orow = out + (size_t)row * 128;
  orow[lane]      = s2*l0;
  orow[lane + 64] = s2*l1;
}

__global__ __launch_bounds__(256)
void adj_copy_kernel(const int* __restrict__ adj, float* __restrict__ o, int m)
{
  int i = blockIdx.x * 256 + threadIdx.x;
  if(i < m) o[i] = (float)adj[i];
}

extern "C" void kernel_launch(void* const* d_in, const int* in_sizes, int n_in,
                              void* d_out, int out_size, void* d_ws, size_t ws_size,
                              hipStream_t stream)
{
  const float* x    = (const float*)d_in[0];
  const int*   adj  = (const int*)  d_in[1];
  const float* w    = (const float*)d_in[2];
  const float* W    = (const float*)d_in[3];
  const float* bias = (const float*)d_in[4];
  const int n = in_sizes[0] / 128;   // 50000
  const int E = in_sizes[2];         // 800000

  float* out     = (float*)d_out;
  float* adj_out = out + (size_t)n * 128;

  // workspace layout
  char* ws = (char*)d_ws;
  float* ht     = (float*)ws;                         ws += (size_t)n * 128 * sizeof(float);
  int*   cnt    = (int*)ws;                           ws += (size_t)n * sizeof(int);       // doubles as cursor
  int*   offs   = (int*)ws;                           ws += (size_t)(n + 1) * sizeof(int);
  int*   bsum   = (int*)ws;                           ws += 256 * sizeof(int);
  int*   sidx   = (int*)ws;                           ws += (size_t)E * sizeof(int);
  float* wval   = (float*)ws;

  const int nb = (n + 255) / 256;   // 196 <= 256

  hipMemsetAsync(cnt, 0, (size_t)n * sizeof(int), stream);
  stageA_kernel<<<512, 256, 0, stream>>>(x, W, bias, ht, n);
  count_kernel<<<(E + 255) / 256, 256, 0, stream>>>(adj, cnt, E);
  scan1_kernel<<<nb, 256, 0, stream>>>(cnt, offs, bsum, n);
  scan2_kernel<<<1, 256, 0, stream>>>(bsum, offs, nb, n, E);
  scan3_kernel<<<nb, 256, 0, stream>>>(offs, bsum, cnt, n);   // cnt becomes cursor
  scatter_kernel<<<(E + 255) / 256, 256, 0, stream>>>(adj, w, cnt, sidx, wval, E);
  agg_act_kernel<<<(n + 3) / 4, 256, 0, stream>>>(offs, sidx, wval, ht, out, n);
  adj_copy_kernel<<<(2 * E + 255) / 256, 256, 0, stream>>>(adj, adj_out, 2 * E);
}

// Round 3
// 265.770 us; speedup vs baseline: 5.8815x; 1.3307x over previous
//
#include <hip/hip_runtime.h>
#include <math.h>

#define MAXN 0.996f
#define MINN 1e-15f

typedef __bf16 bf16x8 __attribute__((ext_vector_type(8)));
typedef float  floatx4 __attribute__((ext_vector_type(4)));

__device__ __forceinline__ float wsum(float v){
  v += __shfl_xor(v, 32);
  v += __shfl_xor(v, 16);
  v += __shfl_xor(v, 8);
  v += __shfl_xor(v, 4);
  v += __shfl_xor(v, 2);
  v += __shfl_xor(v, 1);
  return v;
}

__device__ __forceinline__ float artanh_(float v){
  v = fminf(fmaxf(v, -1.f + 1e-7f), 1.f - 1e-7f);
  return 0.5f * (log1pf(v) - log1pf(-v));
}

// Stage A: ht = logmap0(proj(mobius_add(proj(mobius_matvec(W,x)), hyp_bias)))
// mx = x@W^T via bf16 MFMA 16x16x32. One wave = 16 rows x 128 cols (8 tiles x 4 K-steps).
// W in LDS as bf16, XOR-swizzled at 16B granularity (k16 ^= n&15) for conflict-min b128 reads.
__global__ __launch_bounds__(256)
void stageA_kernel(const float* __restrict__ x, const float* __restrict__ W,
                   const float* __restrict__ bias, float* __restrict__ ht, int n)
{
  __shared__ __bf16 Wl[128 * 128];
  __shared__ float hb_lds[128];
  __shared__ float y2_lds;

  // stage W fp32 -> bf16 LDS (swizzled): 2048 groups of 8 elems, 256 threads x 8 iters
  for(int g = threadIdx.x; g < 2048; g += 256){
    int nr = g >> 4, k16 = g & 15;
    const float* wp = W + nr * 128 + k16 * 8;
    float4 a = *(const float4*)wp;
    float4 b = *(const float4*)(wp + 4);
    bf16x8 f;
    f[0]=(__bf16)a.x; f[1]=(__bf16)a.y; f[2]=(__bf16)a.z; f[3]=(__bf16)a.w;
    f[4]=(__bf16)b.x; f[5]=(__bf16)b.y; f[6]=(__bf16)b.z; f[7]=(__bf16)b.w;
    *(bf16x8*)&Wl[nr * 128 + ((k16 ^ (nr & 15)) << 3)] = f;
  }
  // wave 0: hyp_bias = proj(expmap0(bias)) and y2 = ||hb||^2
  if(threadIdx.x < 64){
    int l = threadIdx.x;
    float b0 = bias[l], b1 = bias[l + 64];
    float bn = fmaxf(sqrtf(wsum(b0*b0 + b1*b1)), MINN);
    float sb = tanhf(bn) / bn;
    float hb0 = sb*b0, hb1 = sb*b1;
    float hnn = fmaxf(sqrtf(wsum(hb0*hb0 + hb1*hb1)), MINN);
    if(hnn > MAXN){ float f = MAXN/hnn; hb0 *= f; hb1 *= f; }
    float y2 = wsum(hb0*hb0 + hb1*hb1);
    hb_lds[l] = hb0; hb_lds[l + 64] = hb1;
    if(l == 0) y2_lds = y2;
  }
  __syncthreads();

  const int lane = threadIdx.x & 63;
  const int wid  = threadIdx.x >> 6;
  const int q    = lane >> 4;     // quad 0..3
  const int n15  = lane & 15;
  const int M0   = blockIdx.x * 64 + wid * 16;
  if(M0 >= n) return;

  floatx4 acc[8];
#pragma unroll
  for(int t = 0; t < 8; t++) acc[t] = (floatx4){0.f,0.f,0.f,0.f};

  float x2p = 0.f;
  int m = M0 + n15; if(m > n - 1) m = n - 1;   // clamp for tail block
#pragma unroll
  for(int kk = 0; kk < 4; kk++){
    const float* xp = x + (size_t)m * 128 + kk * 32 + q * 8;
    float4 xa = *(const float4*)xp;
    float4 xb = *(const float4*)(xp + 4);
    x2p += xa.x*xa.x + xa.y*xa.y + xa.z*xa.z + xa.w*xa.w
         + xb.x*xb.x + xb.y*xb.y + xb.z*xb.z + xb.w*xb.w;
    bf16x8 a;
    a[0]=(__bf16)xa.x; a[1]=(__bf16)xa.y; a[2]=(__bf16)xa.z; a[3]=(__bf16)xa.w;
    a[4]=(__bf16)xb.x; a[5]=(__bf16)xb.y; a[6]=(__bf16)xb.z; a[7]=(__bf16)xb.w;
    int k16 = kk * 4 + q;
#pragma unroll
    for(int t = 0; t < 8; t++){
      bf16x8 b = *(bf16x8*)&Wl[(t*16 + n15) * 128 + ((k16 ^ n15) << 3)];
      acc[t] = __builtin_amdgcn_mfma_f32_16x16x32_bf16(a, b, acc[t], 0, 0, 0);
    }
  }
  // x2p: lane covers 32 k's; sum over quads -> lane holds ||x_{M0+n15}||^2
  x2p += __shfl_xor(x2p, 16);
  x2p += __shfl_xor(x2p, 32);

  float hbv[8];
#pragma unroll
  for(int t = 0; t < 8; t++) hbv[t] = hb_lds[t*16 + n15];
  const float y2 = y2_lds;

#pragma unroll
  for(int i = 0; i < 4; i++){
    const int row  = q * 4 + i;        // local row 0..15
    const int grow = M0 + row;
    // mx2 and mx.hb over 128 cols: per-lane over 8 tiles, then 16-lane group reduce
    float mp = 0.f, dp = 0.f;
#pragma unroll
    for(int t = 0; t < 8; t++){ float v = acc[t][i]; mp = fmaf(v, v, mp); dp = fmaf(v, hbv[t], dp); }
    mp += __shfl_xor(mp, 1); mp += __shfl_xor(mp, 2); mp += __shfl_xor(mp, 4); mp += __shfl_xor(mp, 8);
    dp += __shfl_xor(dp, 1); dp += __shfl_xor(dp, 2); dp += __shfl_xor(dp, 4); dp += __shfl_xor(dp, 8);
    float X2  = __shfl(x2p, row);      // lane 'row' holds ||x_row||^2
    float mxn = fmaxf(sqrtf(mp), MINN);
    float xn  = fmaxf(sqrtf(X2), MINN);
    float tt  = tanhf(mxn / xn * artanh_(xn));
    float s1  = tt / mxn;
    float rn  = fmaxf(tt, MINN);
    if(rn > MAXN) s1 *= MAXN / rn;
    float xy    = s1 * dp;
    float r2    = s1 * s1 * mp;
    float alpha = 1.f + 2.f*xy + y2;
    float beta  = 1.f - r2;
    float inv   = 1.f / fmaxf(1.f + 2.f*xy + r2*y2, MINN);
    float as1   = alpha * s1;
    float uv[8];
    float u2p = 0.f;
#pragma unroll
    for(int t = 0; t < 8; t++){
      uv[t] = (as1 * acc[t][i] + beta * hbv[t]) * inv;
      u2p = fmaf(uv[t], uv[t], u2p);
    }
    u2p += __shfl_xor(u2p, 1); u2p += __shfl_xor(u2p, 2); u2p += __shfl_xor(u2p, 4); u2p += __shfl_xor(u2p, 8);
    float un = fmaxf(sqrtf(u2p), MINN);
    float sc = 1.f, hn = un;
    if(un > MAXN){ sc = MAXN/un; hn = MAXN; }
    float lt = artanh_(hn) / hn * sc;
    if(grow < n){
      float* hr = ht + (size_t)grow * 128;
#pragma unroll
      for(int t = 0; t < 8; t++) hr[t*16 + n15] = lt * uv[t];
    }
  }
}

// ---------------- CSR build ----------------
__global__ __launch_bounds__(256)
void count_kernel(const int* __restrict__ adj, int* __restrict__ cnt, int E)
{
  int e = blockIdx.x * 256 + threadIdx.x;
  if(e < E) atomicAdd(&cnt[adj[e + E]], 1);
}

__global__ __launch_bounds__(256)
void scan1_kernel(const int* __restrict__ cnt, int* __restrict__ offs,
                  int* __restrict__ bsum, int n)
{
  int i = blockIdx.x * 256 + threadIdx.x;
  int lane = threadIdx.x & 63, wid = threadIdx.x >> 6;
  int v = (i < n) ? cnt[i] : 0;
  int iv = v;
#pragma unroll
  for(int o = 1; o < 64; o <<= 1){
    int t = __shfl_up(iv, o);
    if(lane >= o) iv += t;
  }
  __shared__ int wsums[4];
  if(lane == 63) wsums[wid] = iv;
  __syncthreads();
  int wbase = 0;
  for(int k = 0; k < wid; k++) wbase += wsums[k];
  if(i < n) offs[i] = wbase + iv - v;
  if(threadIdx.x == 255) bsum[blockIdx.x] = wbase + iv;
}

__global__ __launch_bounds__(256)
void scan2_kernel(int* __restrict__ bsum, int* __restrict__ offs, int nb, int n, int E)
{
  int t = threadIdx.x;
  int lane = t & 63, wid = t >> 6;
  int v = (t < nb) ? bsum[t] : 0;
  int iv = v;
#pragma unroll
  for(int o = 1; o < 64; o <<= 1){
    int s = __shfl_up(iv, o);
    if(lane >= o) iv += s;
  }
  __shared__ int wsums[4];
  if(lane == 63) wsums[wid] = iv;
  __syncthreads();
  int wbase = 0;
  for(int k = 0; k < wid; k++) wbase += wsums[k];
  int excl = wbase + iv - v;
  __syncthreads();
  if(t < nb) bsum[t] = excl;
  if(t == 0) offs[n] = E;
}

__global__ __launch_bounds__(256)
void scan3_kernel(int* __restrict__ offs, const int* __restrict__ bsum,
                  int* __restrict__ cursor, int n)
{
  int i = blockIdx.x * 256 + threadIdx.x;
  if(i < n){
    int o = offs[i] + bsum[blockIdx.x];
    offs[i] = o;
    cursor[i] = o;
  }
}

__global__ __launch_bounds__(256)
void scatter_kernel(const int* __restrict__ adj, const float* __restrict__ w,
                    int* __restrict__ cursor, int* __restrict__ sidx,
                    float* __restrict__ wval, int E)
{
  int e = blockIdx.x * 256 + threadIdx.x;
  if(e >= E) return;
  int r = adj[e + E];
  int idx = atomicAdd(&cursor[r], 1);
  sidx[idx] = adj[e];
  wval[idx] = w[e];
}

// ---------------- fused aggregate + HypAct ----------------
// One wave per row; half-wave per edge: lanes 0-31 gather a full 512B ht row as float4.
__global__ __launch_bounds__(256)
void agg_act_kernel(const int* __restrict__ offs, const int* __restrict__ sidx,
                    const float* __restrict__ wval, const float* __restrict__ ht,
                    float* __restrict__ out, int n)
{
  int row = blockIdx.x * 4 + (threadIdx.x >> 6);
  if(row >= n) return;
  int lane = threadIdx.x & 63;
  int h = lane >> 5;        // half 0/1
  int c = lane & 31;        // dims [4c, 4c+4)
  int beg = offs[row], end = offs[row + 1];

  float4 acc = {0.f, 0.f, 0.f, 0.f};
  for(int j = beg; j < end; j += 64){
    int m = end - j; if(m > 64) m = 64;
    int sv = 0; float wv = 0.f;
    if(lane < m){ sv = sidx[j + lane]; wv = wval[j + lane]; }
    for(int t = h; t < m; t += 2){
      int s    = __shfl(sv, t);
      float we = __shfl(wv, t);
      const float4 v = *(const float4*)(ht + (size_t)s * 128 + 4 * c);
      acc.x = fmaf(we, v.x, acc.x);
      acc.y = fmaf(we, v.y, acc.y);
      acc.z = fmaf(we, v.z, acc.z);
      acc.w = fmaf(we, v.w, acc.w);
    }
  }
  // combine the two halves
  acc.x += __shfl_xor(acc.x, 32);
  acc.y += __shfl_xor(acc.y, 32);
  acc.z += __shfl_xor(acc.z, 32);
  acc.w += __shfl_xor(acc.w, 32);

  // HypAct: proj(expmap0(relu(logmap0(proj(expmap0(agg))))))
  float u2p = acc.x*acc.x + acc.y*acc.y + acc.z*acc.z + acc.w*acc.w;
  u2p += __shfl_xor(u2p, 16); u2p += __shfl_xor(u2p, 8);
  u2p += __shfl_xor(u2p, 4);  u2p += __shfl_xor(u2p, 2); u2p += __shfl_xor(u2p, 1);
  float un = fmaxf(sqrtf(u2p), MINN);
  float te = tanhf(un);
  float se = te / un;
  float gn = fmaxf(te, MINN);
  float hn = gn;
  if(gn > MAXN){ se *= MAXN/gn; hn = MAXN; }
  float la = artanh_(hn) / hn * se;
  float4 l;
  l.x = fmaxf(la*acc.x, 0.f); l.y = fmaxf(la*acc.y, 0.f);
  l.z = fmaxf(la*acc.z, 0.f); l.w = fmaxf(la*acc.w, 0.f);
  float r2p = l.x*l.x + l.y*l.y + l.z*l.z + l.w*l.w;
  r2p += __shfl_xor(r2p, 16); r2p += __shfl_xor(r2p, 8);
  r2p += __shfl_xor(r2p, 4);  r2p += __shfl_xor(r2p, 2); r2p += __shfl_xor(r2p, 1);
  float rn = fmaxf(sqrtf(r2p), MINN);
  float t2 = tanhf(rn);
  float s2 = t2 / rn;
  float on = fmaxf(t2, MINN);
  if(on > MAXN) s2 *= MAXN/on;
  if(h == 0){
    float4 o;
    o.x = s2*l.x; o.y = s2*l.y; o.z = s2*l.z; o.w = s2*l.w;
    *(float4*)(out + (size_t)row * 128 + 4 * c) = o;
  }
}

__global__ __launch_bounds__(256)
void adj_copy_kernel(const int* __restrict__ adj, float* __restrict__ o, int m)
{
  int i = blockIdx.x * 256 + threadIdx.x;
  int i4 = i * 4;
  if(i4 + 3 < m){
    int4 v = *(const int4*)(adj + i4);
    float4 f = {(float)v.x, (float)v.y, (float)v.z, (float)v.w};
    *(float4*)(o + i4) = f;
  } else {
    for(int k = i4; k < m; k++) o[k] = (float)adj[k];
  }
}

extern "C" void kernel_launch(void* const* d_in, const int* in_sizes, int n_in,
                              void* d_out, int out_size, void* d_ws, size_t ws_size,
                              hipStream_t stream)
{
  const float* x    = (const float*)d_in[0];
  const int*   adj  = (const int*)  d_in[1];
  const float* w    = (const float*)d_in[2];
  const float* W    = (const float*)d_in[3];
  const float* bias = (const float*)d_in[4];
  const int n = in_sizes[0] / 128;   // 50000
  const int E = in_sizes[2];         // 800000

  float* out     = (float*)d_out;
  float* adj_out = out + (size_t)n * 128;

  char* ws = (char*)d_ws;
  float* ht   = (float*)ws;   ws += (size_t)n * 128 * sizeof(float);
  int*   cnt  = (int*)ws;     ws += (size_t)n * sizeof(int);       // doubles as cursor
  int*   offs = (int*)ws;     ws += (size_t)(n + 1) * sizeof(int);
  int*   bsum = (int*)ws;     ws += 256 * sizeof(int);
  int*   sidx = (int*)ws;     ws += (size_t)E * sizeof(int);
  float* wval = (float*)ws;

  const int nb = (n + 255) / 256;   // 196 <= 256

  hipMemsetAsync(cnt, 0, (size_t)n * sizeof(int), stream);
  stageA_kernel<<<(n + 63) / 64, 256, 0, stream>>>(x, W, bias, ht, n);
  count_kernel<<<(E + 255) / 256, 256, 0, stream>>>(adj, cnt, E);
  scan1_kernel<<<nb, 256, 0, stream>>>(cnt, offs, bsum, n);
  scan2_kernel<<<1, 256, 0, stream>>>(bsum, offs, nb, n, E);
  scan3_kernel<<<nb, 256, 0, stream>>>(offs, bsum, cnt, n);   // cnt becomes cursor
  scatter_kernel<<<(E + 255) / 256, 256, 0, stream>>>(adj, w, cnt, sidx, wval, E);
  agg_act_kernel<<<(n + 3) / 4, 256, 0, stream>>>(offs, sidx, wval, ht, out, n);
  adj_copy_kernel<<<(2 * E + 1023) / 1024, 256, 0, stream>>>(adj, adj_out, 2 * E);
}

// Round 4
// 246.416 us; speedup vs baseline: 6.3435x; 1.0785x over previous
//
#include <hip/hip_runtime.h>
#include <math.h>

#define MAXN 0.996f
#define MINN 1e-15f

typedef __bf16 bf16x8 __attribute__((ext_vector_type(8)));
typedef float  floatx4 __attribute__((ext_vector_type(4)));

__device__ __forceinline__ float wsum(float v){
  v += __shfl_xor(v, 32);
  v += __shfl_xor(v, 16);
  v += __shfl_xor(v, 8);
  v += __shfl_xor(v, 4);
  v += __shfl_xor(v, 2);
  v += __shfl_xor(v, 1);
  return v;
}

__device__ __forceinline__ float artanh_(float v){
  v = fminf(fmaxf(v, -1.f + 1e-7f), 1.f - 1e-7f);
  return 0.5f * (log1pf(v) - log1pf(-v));
}

// Stage A: ht = logmap0(proj(mobius_add(proj(mobius_matvec(W,x)), hyp_bias)))
// Split-bf16 (Dekker) matmul: W = Wh + Wl, x = xh + xl; mx ~= xh*Wh + xh*Wl + xl*Wh
// (rel err ~1e-5). ht stored as bf16 in PERMUTED layout: true dim t*16+i at byte
// position (i*8+t)*2 -> lane writes 16B contiguous; agg reads 16B/lane.
__global__ __launch_bounds__(256)
void stageA_kernel(const float* __restrict__ x, const float* __restrict__ W,
                   const float* __restrict__ bias, __bf16* __restrict__ ht, int n)
{
  __shared__ __bf16 Wh[128 * 128];   // 32 KB
  __shared__ __bf16 Wl[128 * 128];   // 32 KB

  for(int g = threadIdx.x; g < 2048; g += 256){
    int nr = g >> 4, k16 = g & 15;
    const float* wp = W + nr * 128 + k16 * 8;
    float4 a = *(const float4*)wp;
    float4 b = *(const float4*)(wp + 4);
    bf16x8 h, l;
    h[0]=(__bf16)a.x; l[0]=(__bf16)(a.x-(float)h[0]);
    h[1]=(__bf16)a.y; l[1]=(__bf16)(a.y-(float)h[1]);
    h[2]=(__bf16)a.z; l[2]=(__bf16)(a.z-(float)h[2]);
    h[3]=(__bf16)a.w; l[3]=(__bf16)(a.w-(float)h[3]);
    h[4]=(__bf16)b.x; l[4]=(__bf16)(b.x-(float)h[4]);
    h[5]=(__bf16)b.y; l[5]=(__bf16)(b.y-(float)h[5]);
    h[6]=(__bf16)b.z; l[6]=(__bf16)(b.z-(float)h[6]);
    h[7]=(__bf16)b.w; l[7]=(__bf16)(b.w-(float)h[7]);
    int off = nr * 128 + ((k16 ^ (nr & 15)) << 3);
    *(bf16x8*)&Wh[off] = h;
    *(bf16x8*)&Wl[off] = l;
  }
  __syncthreads();

  const int lane = threadIdx.x & 63;
  const int wid  = threadIdx.x >> 6;
  const int q    = lane >> 4;
  const int n15  = lane & 15;

  // per-wave hyp_bias (registers only)
  float b0 = bias[lane], b1 = bias[lane + 64];
  float bn = fmaxf(sqrtf(wsum(b0*b0 + b1*b1)), MINN);
  float sb = tanhf(bn) / bn;
  float hb0 = sb*b0, hb1 = sb*b1;
  float hnn = fmaxf(sqrtf(wsum(hb0*hb0 + hb1*hb1)), MINN);
  if(hnn > MAXN){ float f = MAXN/hnn; hb0 *= f; hb1 *= f; }
  const float y2 = wsum(hb0*hb0 + hb1*hb1);
  float hbv[8];
#pragma unroll
  for(int t = 0; t < 4; t++) hbv[t] = __shfl(hb0, t*16 + n15);
#pragma unroll
  for(int t = 4; t < 8; t++) hbv[t] = __shfl(hb1, (t-4)*16 + n15);

  const int M0 = blockIdx.x * 64 + wid * 16;
  if(M0 >= n) return;

  floatx4 acc[8];
#pragma unroll
  for(int t = 0; t < 8; t++) acc[t] = (floatx4){0.f,0.f,0.f,0.f};

  float x2p = 0.f;
  int m = M0 + n15; if(m > n - 1) m = n - 1;
#pragma unroll
  for(int kk = 0; kk < 4; kk++){
    const float* xp = x + (size_t)m * 128 + kk * 32 + q * 8;
    float4 xa = *(const float4*)xp;
    float4 xb = *(const float4*)(xp + 4);
    x2p += xa.x*xa.x + xa.y*xa.y + xa.z*xa.z + xa.w*xa.w
         + xb.x*xb.x + xb.y*xb.y + xb.z*xb.z + xb.w*xb.w;
    bf16x8 ah, al;
    ah[0]=(__bf16)xa.x; al[0]=(__bf16)(xa.x-(float)ah[0]);
    ah[1]=(__bf16)xa.y; al[1]=(__bf16)(xa.y-(float)ah[1]);
    ah[2]=(__bf16)xa.z; al[2]=(__bf16)(xa.z-(float)ah[2]);
    ah[3]=(__bf16)xa.w; al[3]=(__bf16)(xa.w-(float)ah[3]);
    ah[4]=(__bf16)xb.x; al[4]=(__bf16)(xb.x-(float)ah[4]);
    ah[5]=(__bf16)xb.y; al[5]=(__bf16)(xb.y-(float)ah[5]);
    ah[6]=(__bf16)xb.z; al[6]=(__bf16)(xb.z-(float)ah[6]);
    ah[7]=(__bf16)xb.w; al[7]=(__bf16)(xb.w-(float)ah[7]);
    int k16 = kk * 4 + q;
#pragma unroll
    for(int t = 0; t < 8; t++){
      int off = (t*16 + n15) * 128 + ((k16 ^ n15) << 3);
      bf16x8 bh = *(bf16x8*)&Wh[off];
      bf16x8 bl = *(bf16x8*)&Wl[off];
      acc[t] = __builtin_amdgcn_mfma_f32_16x16x32_bf16(ah, bh, acc[t], 0, 0, 0);
      acc[t] = __builtin_amdgcn_mfma_f32_16x16x32_bf16(ah, bl, acc[t], 0, 0, 0);
      acc[t] = __builtin_amdgcn_mfma_f32_16x16x32_bf16(al, bh, acc[t], 0, 0, 0);
    }
  }
  x2p += __shfl_xor(x2p, 16);
  x2p += __shfl_xor(x2p, 32);

#pragma unroll
  for(int i = 0; i < 4; i++){
    const int row  = q * 4 + i;
    const int grow = M0 + row;
    float mp = 0.f, dp = 0.f;
#pragma unroll
    for(int t = 0; t < 8; t++){ float v = acc[t][i]; mp = fmaf(v, v, mp); dp = fmaf(v, hbv[t], dp); }
    mp += __shfl_xor(mp, 1); mp += __shfl_xor(mp, 2); mp += __shfl_xor(mp, 4); mp += __shfl_xor(mp, 8);
    dp += __shfl_xor(dp, 1); dp += __shfl_xor(dp, 2); dp += __shfl_xor(dp, 4); dp += __shfl_xor(dp, 8);
    float X2  = __shfl(x2p, row);
    float mxn = fmaxf(sqrtf(mp), MINN);
    float xn  = fmaxf(sqrtf(X2), MINN);
    float tt  = tanhf(mxn / xn * artanh_(xn));
    float s1  = tt / mxn;
    float rn  = fmaxf(tt, MINN);
    if(rn > MAXN) s1 *= MAXN / rn;
    float xy    = s1 * dp;
    float r2    = s1 * s1 * mp;
    float alpha = 1.f + 2.f*xy + y2;
    float beta  = 1.f - r2;
    float inv   = 1.f / fmaxf(1.f + 2.f*xy + r2*y2, MINN);
    float as1   = alpha * s1;
    float uv[8];
    float u2p = 0.f;
#pragma unroll
    for(int t = 0; t < 8; t++){
      uv[t] = (as1 * acc[t][i] + beta * hbv[t]) * inv;
      u2p = fmaf(uv[t], uv[t], u2p);
    }
    u2p += __shfl_xor(u2p, 1); u2p += __shfl_xor(u2p, 2); u2p += __shfl_xor(u2p, 4); u2p += __shfl_xor(u2p, 8);
    float un = fmaxf(sqrtf(u2p), MINN);
    float sc = 1.f, hn = un;
    if(un > MAXN){ sc = MAXN/un; hn = MAXN; }
    float lt = artanh_(hn) / hn * sc;
    if(grow < n){
      bf16x8 f;
#pragma unroll
      for(int t = 0; t < 8; t++) f[t] = (__bf16)(lt * uv[t]);
      *(bf16x8*)(ht + (size_t)grow * 128 + n15 * 8) = f;   // permuted, 16B coalesced
    }
  }
}

// ---------------- adj -> float copy, fused with dest counting ----------------
__global__ __launch_bounds__(256)
void adjcopy_count_kernel(const int* __restrict__ adj, float* __restrict__ o,
                          int* __restrict__ cnt, int E)
{
  int idx = blockIdx.x * 256 + threadIdx.x;
  int i4 = idx * 4;
  int m2 = 2 * E;
  if(i4 + 3 < m2){
    int4 v = *(const int4*)(adj + i4);
    float4 f = {(float)v.x, (float)v.y, (float)v.z, (float)v.w};
    *(float4*)(o + i4) = f;
    if(i4 >= E){
      atomicAdd(&cnt[v.x], 1); atomicAdd(&cnt[v.y], 1);
      atomicAdd(&cnt[v.z], 1); atomicAdd(&cnt[v.w], 1);
    } else if(i4 + 3 >= E){
      if(i4 + 0 >= E) atomicAdd(&cnt[v.x], 1);
      if(i4 + 1 >= E) atomicAdd(&cnt[v.y], 1);
      if(i4 + 2 >= E) atomicAdd(&cnt[v.z], 1);
      if(i4 + 3 >= E) atomicAdd(&cnt[v.w], 1);
    }
  } else {
    for(int k = i4; k < m2; k++){
      int v = adj[k];
      o[k] = (float)v;
      if(k >= E) atomicAdd(&cnt[v], 1);
    }
  }
}

// ---------------- scans ----------------
__global__ __launch_bounds__(256)
void scan1_kernel(const int* __restrict__ cnt, int* __restrict__ offs,
                  int* __restrict__ bsum, int n)
{
  int i = blockIdx.x * 256 + threadIdx.x;
  int lane = threadIdx.x & 63, wid = threadIdx.x >> 6;
  int v = (i < n) ? cnt[i] : 0;
  int iv = v;
#pragma unroll
  for(int o = 1; o < 64; o <<= 1){
    int t = __shfl_up(iv, o);
    if(lane >= o) iv += t;
  }
  __shared__ int wsums[4];
  if(lane == 63) wsums[wid] = iv;
  __syncthreads();
  int wbase = 0;
  for(int k = 0; k < wid; k++) wbase += wsums[k];
  if(i < n) offs[i] = wbase + iv - v;
  if(threadIdx.x == 255) bsum[blockIdx.x] = wbase + iv;
}

__global__ __launch_bounds__(256)
void scan2_kernel(int* __restrict__ bsum, int* __restrict__ offs, int nb, int n, int E)
{
  int t = threadIdx.x;
  int lane = t & 63, wid = t >> 6;
  int v = (t < nb) ? bsum[t] : 0;
  int iv = v;
#pragma unroll
  for(int o = 1; o < 64; o <<= 1){
    int s = __shfl_up(iv, o);
    if(lane >= o) iv += s;
  }
  __shared__ int wsums[4];
  if(lane == 63) wsums[wid] = iv;
  __syncthreads();
  int wbase = 0;
  for(int k = 0; k < wid; k++) wbase += wsums[k];
  int excl = wbase + iv - v;
  __syncthreads();
  if(t < nb) bsum[t] = excl;
  if(t == 0) offs[n] = E;
}

__global__ __launch_bounds__(256)
void scan3_kernel(int* __restrict__ offs, const int* __restrict__ bsum,
                  int* __restrict__ cursor, int n)
{
  int i = blockIdx.x * 256 + threadIdx.x;
  if(i < n){
    int o = offs[i] + bsum[blockIdx.x];
    offs[i] = o;
    cursor[i] = o;
  }
}

// scatter (src,weight) packed as int2 -> one 8B scattered store per edge
__global__ __launch_bounds__(256)
void scatter_kernel(const int* __restrict__ adj, const float* __restrict__ w,
                    int* __restrict__ cursor, int2* __restrict__ epk, int E)
{
  int e = blockIdx.x * 256 + threadIdx.x;
  if(e >= E) return;
  int r = adj[e + E];
  int idx = atomicAdd(&cursor[r], 1);
  int2 p; p.x = adj[e]; p.y = __float_as_int(w[e]);
  epk[idx] = p;
}

// ---------------- fused aggregate + HypAct ----------------
// One wave per row; 16 lanes per edge (bf16x8 = 16B/lane), 4 edges/wave, unroll 2.
__global__ __launch_bounds__(256)
void agg_act_kernel(const int* __restrict__ offs, const int2* __restrict__ epk,
                    const __bf16* __restrict__ ht, float* __restrict__ out, int n)
{
  __shared__ float tr[4][128];
  int wid = threadIdx.x >> 6;
  int row = blockIdx.x * 4 + wid;
  if(row >= n) return;
  int lane = threadIdx.x & 63;
  int g = lane >> 4, i = lane & 15;
  int beg = offs[row], end = offs[row + 1];

  float acc[8] = {0.f,0.f,0.f,0.f,0.f,0.f,0.f,0.f};
  for(int j = beg; j < end; j += 64){
    int m = end - j; if(m > 64) m = 64;
    int sv = 0; float wv = 0.f;
    if(lane < m){ int2 p = epk[j + lane]; sv = p.x; wv = __int_as_float(p.y); }
    int iters = (m + 3) >> 2;
    int it = 0;
    for(; it + 1 < iters; it += 2){
      int t0 = it*4 + g, t1 = t0 + 4;
      float w0 = __shfl(wv, t0);            // t0 < m guaranteed here
      int   s0 = __shfl(sv, t0);
      float w1 = (t1 < m) ? __shfl(wv, t1) : 0.f;
      int   s1 = (t1 < m) ? __shfl(sv, t1) : s0;
      bf16x8 v0 = *(const bf16x8*)(ht + (size_t)s0 * 128 + i * 8);
      bf16x8 v1 = *(const bf16x8*)(ht + (size_t)s1 * 128 + i * 8);
#pragma unroll
      for(int k = 0; k < 8; k++) acc[k] = fmaf(w0, (float)v0[k], acc[k]);
#pragma unroll
      for(int k = 0; k < 8; k++) acc[k] = fmaf(w1, (float)v1[k], acc[k]);
    }
    if(it < iters){
      int t0 = it*4 + g;
      float w0 = (t0 < m) ? __shfl(wv, t0) : 0.f;
      int   s0 = (t0 < m) ? __shfl(sv, t0) : __shfl(sv, 0);
      bf16x8 v0 = *(const bf16x8*)(ht + (size_t)s0 * 128 + i * 8);
#pragma unroll
      for(int k = 0; k < 8; k++) acc[k] = fmaf(w0, (float)v0[k], acc[k]);
    }
  }
  // combine the 4 edge-groups (same dims, lane i aligned mod 16)
#pragma unroll
  for(int k = 0; k < 8; k++){
    acc[k] += __shfl_xor(acc[k], 16);
    acc[k] += __shfl_xor(acc[k], 32);
  }

  // HypAct: proj(expmap0(relu(logmap0(proj(expmap0(agg))))))
  float u2p = 0.f;
#pragma unroll
  for(int k = 0; k < 8; k++) u2p = fmaf(acc[k], acc[k], u2p);
  u2p += __shfl_xor(u2p, 1); u2p += __shfl_xor(u2p, 2);
  u2p += __shfl_xor(u2p, 4); u2p += __shfl_xor(u2p, 8);
  float un = fmaxf(sqrtf(u2p), MINN);
  float te = tanhf(un);
  float se = te / un;
  float gn = fmaxf(te, MINN);
  float hn = gn;
  if(gn > MAXN){ se *= MAXN/gn; hn = MAXN; }
  float la = artanh_(hn) / hn * se;
  float l[8];
  float r2p = 0.f;
#pragma unroll
  for(int k = 0; k < 8; k++){ l[k] = fmaxf(la*acc[k], 0.f); r2p = fmaf(l[k], l[k], r2p); }
  r2p += __shfl_xor(r2p, 1); r2p += __shfl_xor(r2p, 2);
  r2p += __shfl_xor(r2p, 4); r2p += __shfl_xor(r2p, 8);
  float rn = fmaxf(sqrtf(r2p), MINN);
  float t2 = tanhf(rn);
  float s2 = t2 / rn;
  float on = fmaxf(t2, MINN);
  if(on > MAXN) s2 *= MAXN/on;

  // un-permute via LDS: true dim of acc[k] is k*16+i
  if(g == 0){
#pragma unroll
    for(int k = 0; k < 8; k++) tr[wid][k*16 + i] = s2 * l[k];
  }
  float2 o = *(float2*)&tr[wid][lane * 2];
  *(float2*)(out + (size_t)row * 128 + lane * 2) = o;
}

extern "C" void kernel_launch(void* const* d_in, const int* in_sizes, int n_in,
                              void* d_out, int out_size, void* d_ws, size_t ws_size,
                              hipStream_t stream)
{
  const float* x    = (const float*)d_in[0];
  const int*   adj  = (const int*)  d_in[1];
  const float* w    = (const float*)d_in[2];
  const float* W    = (const float*)d_in[3];
  const float* bias = (const float*)d_in[4];
  const int n = in_sizes[0] / 128;   // 50000
  const int E = in_sizes[2];         // 800000

  float* out     = (float*)d_out;
  float* adj_out = out + (size_t)n * 128;

  char* ws = (char*)d_ws;
  __bf16* ht  = (__bf16*)ws;  ws += (size_t)n * 128 * sizeof(__bf16);
  int*   cnt  = (int*)ws;     ws += (size_t)n * sizeof(int);       // doubles as cursor
  int*   offs = (int*)ws;     ws += (size_t)(n + 1) * sizeof(int);
  int*   bsum = (int*)ws;     ws += 256 * sizeof(int);
  int2*  epk  = (int2*)ws;

  const int nb = (n + 255) / 256;

  hipMemsetAsync(cnt, 0, (size_t)n * sizeof(int), stream);
  stageA_kernel<<<(n + 63) / 64, 256, 0, stream>>>(x, W, bias, ht, n);
  adjcopy_count_kernel<<<(2 * E / 4 + 255) / 256, 256, 0, stream>>>(adj, adj_out, cnt, E);
  scan1_kernel<<<nb, 256, 0, stream>>>(cnt, offs, bsum, n);
  scan2_kernel<<<1, 256, 0, stream>>>(bsum, offs, nb, n, E);
  scan3_kernel<<<nb, 256, 0, stream>>>(offs, bsum, cnt, n);   // cnt becomes cursor
  scatter_kernel<<<(E + 255) / 256, 256, 0, stream>>>(adj, w, cnt, epk, E);
  agg_act_kernel<<<(n + 3) / 4, 256, 0, stream>>>(offs, epk, ht, out, n);
}

// Round 5
// 189.968 us; speedup vs baseline: 8.2284x; 1.2971x over previous
//
#include <hip/hip_runtime.h>
#include <math.h>

#define MAXN 0.996f
#define MINN 1e-15f
#define CAP  5120          // per-bucket staging capacity (mean 4096, sd ~64)

typedef __bf16   bf16x8 __attribute__((ext_vector_type(8)));
typedef _Float16 halfx8 __attribute__((ext_vector_type(8)));
typedef float    floatx4 __attribute__((ext_vector_type(4)));

__device__ __forceinline__ float wsum(float v){
  v += __shfl_xor(v, 32);
  v += __shfl_xor(v, 16);
  v += __shfl_xor(v, 8);
  v += __shfl_xor(v, 4);
  v += __shfl_xor(v, 2);
  v += __shfl_xor(v, 1);
  return v;
}

__device__ __forceinline__ float artanh_(float v){
  v = fminf(fmaxf(v, -1.f + 1e-7f), 1.f - 1e-7f);
  return 0.5f * (log1pf(v) - log1pf(-v));
}

// block-wide (256 thr) exclusive scan; wsums = LDS[4]; contains one __syncthreads
__device__ __forceinline__ int block_excl_scan(int v, int tid, int* wsums){
  int lane = tid & 63, wid = tid >> 6;
  int iv = v;
#pragma unroll
  for(int o = 1; o < 64; o <<= 1){
    int t = __shfl_up(iv, o);
    if(lane >= o) iv += t;
  }
  if(lane == 63) wsums[wid] = iv;
  __syncthreads();
  int wbase = 0;
  for(int k = 0; k < wid; k++) wbase += wsums[k];
  return wbase + iv - v;
}

// ---------------- Stage A (unchanged math; ht now fp16, permuted layout) ----------------
__global__ __launch_bounds__(256)
void stageA_kernel(const float* __restrict__ x, const float* __restrict__ W,
                   const float* __restrict__ bias, _Float16* __restrict__ ht, int n)
{
  __shared__ __bf16 Wh[128 * 128];
  __shared__ __bf16 Wl[128 * 128];

  for(int g = threadIdx.x; g < 2048; g += 256){
    int nr = g >> 4, k16 = g & 15;
    const float* wp = W + nr * 128 + k16 * 8;
    float4 a = *(const float4*)wp;
    float4 b = *(const float4*)(wp + 4);
    bf16x8 h, l;
    h[0]=(__bf16)a.x; l[0]=(__bf16)(a.x-(float)h[0]);
    h[1]=(__bf16)a.y; l[1]=(__bf16)(a.y-(float)h[1]);
    h[2]=(__bf16)a.z; l[2]=(__bf16)(a.z-(float)h[2]);
    h[3]=(__bf16)a.w; l[3]=(__bf16)(a.w-(float)h[3]);
    h[4]=(__bf16)b.x; l[4]=(__bf16)(b.x-(float)h[4]);
    h[5]=(__bf16)b.y; l[5]=(__bf16)(b.y-(float)h[5]);
    h[6]=(__bf16)b.z; l[6]=(__bf16)(b.z-(float)h[6]);
    h[7]=(__bf16)b.w; l[7]=(__bf16)(b.w-(float)h[7]);
    int off = nr * 128 + ((k16 ^ (nr & 15)) << 3);
    *(bf16x8*)&Wh[off] = h;
    *(bf16x8*)&Wl[off] = l;
  }
  __syncthreads();

  const int lane = threadIdx.x & 63;
  const int wid  = threadIdx.x >> 6;
  const int q    = lane >> 4;
  const int n15  = lane & 15;

  float b0 = bias[lane], b1 = bias[lane + 64];
  float bn = fmaxf(sqrtf(wsum(b0*b0 + b1*b1)), MINN);
  float sb = tanhf(bn) / bn;
  float hb0 = sb*b0, hb1 = sb*b1;
  float hnn = fmaxf(sqrtf(wsum(hb0*hb0 + hb1*hb1)), MINN);
  if(hnn > MAXN){ float f = MAXN/hnn; hb0 *= f; hb1 *= f; }
  const float y2 = wsum(hb0*hb0 + hb1*hb1);
  float hbv[8];
#pragma unroll
  for(int t = 0; t < 4; t++) hbv[t] = __shfl(hb0, t*16 + n15);
#pragma unroll
  for(int t = 4; t < 8; t++) hbv[t] = __shfl(hb1, (t-4)*16 + n15);

  const int M0 = blockIdx.x * 64 + wid * 16;
  if(M0 >= n) return;

  floatx4 acc[8];
#pragma unroll
  for(int t = 0; t < 8; t++) acc[t] = (floatx4){0.f,0.f,0.f,0.f};

  float x2p = 0.f;
  int m = M0 + n15; if(m > n - 1) m = n - 1;
#pragma unroll
  for(int kk = 0; kk < 4; kk++){
    const float* xp = x + (size_t)m * 128 + kk * 32 + q * 8;
    float4 xa = *(const float4*)xp;
    float4 xb = *(const float4*)(xp + 4);
    x2p += xa.x*xa.x + xa.y*xa.y + xa.z*xa.z + xa.w*xa.w
         + xb.x*xb.x + xb.y*xb.y + xb.z*xb.z + xb.w*xb.w;
    bf16x8 ah, al;
    ah[0]=(__bf16)xa.x; al[0]=(__bf16)(xa.x-(float)ah[0]);
    ah[1]=(__bf16)xa.y; al[1]=(__bf16)(xa.y-(float)ah[1]);
    ah[2]=(__bf16)xa.z; al[2]=(__bf16)(xa.z-(float)ah[2]);
    ah[3]=(__bf16)xa.w; al[3]=(__bf16)(xa.w-(float)ah[3]);
    ah[4]=(__bf16)xb.x; al[4]=(__bf16)(xb.x-(float)ah[4]);
    ah[5]=(__bf16)xb.y; al[5]=(__bf16)(xb.y-(float)ah[5]);
    ah[6]=(__bf16)xb.z; al[6]=(__bf16)(xb.z-(float)ah[6]);
    ah[7]=(__bf16)xb.w; al[7]=(__bf16)(xb.w-(float)ah[7]);
    int k16 = kk * 4 + q;
#pragma unroll
    for(int t = 0; t < 8; t++){
      int off = (t*16 + n15) * 128 + ((k16 ^ n15) << 3);
      bf16x8 bh = *(bf16x8*)&Wh[off];
      bf16x8 bl = *(bf16x8*)&Wl[off];
      acc[t] = __builtin_amdgcn_mfma_f32_16x16x32_bf16(ah, bh, acc[t], 0, 0, 0);
      acc[t] = __builtin_amdgcn_mfma_f32_16x16x32_bf16(ah, bl, acc[t], 0, 0, 0);
      acc[t] = __builtin_amdgcn_mfma_f32_16x16x32_bf16(al, bh, acc[t], 0, 0, 0);
    }
  }
  x2p += __shfl_xor(x2p, 16);
  x2p += __shfl_xor(x2p, 32);

#pragma unroll
  for(int i = 0; i < 4; i++){
    const int row  = q * 4 + i;
    const int grow = M0 + row;
    float mp = 0.f, dp = 0.f;
#pragma unroll
    for(int t = 0; t < 8; t++){ float v = acc[t][i]; mp = fmaf(v, v, mp); dp = fmaf(v, hbv[t], dp); }
    mp += __shfl_xor(mp, 1); mp += __shfl_xor(mp, 2); mp += __shfl_xor(mp, 4); mp += __shfl_xor(mp, 8);
    dp += __shfl_xor(dp, 1); dp += __shfl_xor(dp, 2); dp += __shfl_xor(dp, 4); dp += __shfl_xor(dp, 8);
    float X2  = __shfl(x2p, row);
    float mxn = fmaxf(sqrtf(mp), MINN);
    float xn  = fmaxf(sqrtf(X2), MINN);
    float tt  = tanhf(mxn / xn * artanh_(xn));
    float s1  = tt / mxn;
    float rn  = fmaxf(tt, MINN);
    if(rn > MAXN) s1 *= MAXN / rn;
    float xy    = s1 * dp;
    float r2    = s1 * s1 * mp;
    float alpha = 1.f + 2.f*xy + y2;
    float beta  = 1.f - r2;
    float inv   = 1.f / fmaxf(1.f + 2.f*xy + r2*y2, MINN);
    float as1   = alpha * s1;
    float uv[8];
    float u2p = 0.f;
#pragma unroll
    for(int t = 0; t < 8; t++){
      uv[t] = (as1 * acc[t][i] + beta * hbv[t]) * inv;
      u2p = fmaf(uv[t], uv[t], u2p);
    }
    u2p += __shfl_xor(u2p, 1); u2p += __shfl_xor(u2p, 2); u2p += __shfl_xor(u2p, 4); u2p += __shfl_xor(u2p, 8);
    float un = fmaxf(sqrtf(u2p), MINN);
    float sc = 1.f, hn = un;
    if(un > MAXN){ sc = MAXN/un; hn = MAXN; }
    float lt = artanh_(hn) / hn * sc;
    if(grow < n){
      halfx8 f;
#pragma unroll
      for(int t = 0; t < 8; t++) f[t] = (_Float16)(lt * uv[t]);
      *(halfx8*)(ht + (size_t)grow * 128 + n15 * 8) = f;
    }
  }
}

// ---------------- Pass A: bucket partition (b = r>>8) + adj->float copy ----------------
// 4096 edges/block. Payload: p0 = s | (rlo<<16) | (b<<24), p1 = w bits.
__global__ __launch_bounds__(256)
void passA_kernel(const int* __restrict__ adj, const float* __restrict__ w,
                  float* __restrict__ adj_out, int* __restrict__ bucketSize,
                  int2* __restrict__ part, int E)
{
  __shared__ int hist[256];
  __shared__ int lbase[256];
  __shared__ int gbase[256];
  __shared__ int cursor[256];
  __shared__ int wsA[4];
  __shared__ int2 stag[4096];

  const int tid = threadIdx.x;
  hist[tid] = 0; cursor[tid] = 0;
  __syncthreads();

  const int e0 = blockIdx.x * 4096;
  int p0r[16], p1r[16];
#pragma unroll
  for(int k = 0; k < 16; k++){
    int e = e0 + k*256 + tid;
    if(e < E){
      int s = adj[e];
      int r = adj[e + E];
      float we = w[e];
      adj_out[e]     = (float)s;
      adj_out[e + E] = (float)r;
      int b = r >> 8;
      p0r[k] = s | ((r & 255) << 16) | (b << 24);
      p1r[k] = __float_as_int(we);
      atomicAdd(&hist[b], 1);
    }
  }
  __syncthreads();
  int cb = hist[tid];
  lbase[tid] = block_excl_scan(cb, tid, wsA);   // contains a sync
  __syncthreads();
  gbase[tid] = cb ? atomicAdd(&bucketSize[tid], cb) : 0;
  __syncthreads();
#pragma unroll
  for(int k = 0; k < 16; k++){
    int e = e0 + k*256 + tid;
    if(e < E){
      int b = ((unsigned)p0r[k]) >> 24;
      int pos = lbase[b] + atomicAdd(&cursor[b], 1);
      stag[pos] = make_int2(p0r[k], p1r[k]);
    }
  }
  __syncthreads();
  int total = (e0 + 4096 <= E) ? 4096 : (E - e0);
  for(int i = tid; i < total; i += 256){
    int2 p = stag[i];
    int b = ((unsigned)p.x) >> 24;
    int loc = gbase[b] + (i - lbase[b]);
    if(loc < CAP) part[(size_t)b * CAP + loc] = p;   // defensive clamp
  }
}

// ---------------- Pass B: per-bucket local CSR; writes offs + epk ----------------
__global__ __launch_bounds__(256)
void passB_kernel(const int* __restrict__ bucketSize, const int2* __restrict__ part,
                  int2* __restrict__ epk, int* __restrict__ offs, int n)
{
  __shared__ int sizes[256];
  __shared__ int sbase[256];
  __shared__ int hist[256];
  __shared__ int rowbase[256];
  __shared__ int cursor[256];
  __shared__ int wsA[4];
  __shared__ int2 stag[CAP];

  const int tid = threadIdx.x;
  const int b   = blockIdx.x;
  sizes[tid] = bucketSize[tid];
  hist[tid]  = 0;
  __syncthreads();
  sbase[tid] = block_excl_scan(sizes[tid], tid, wsA);   // contains a sync
  __syncthreads();
  const int base_b = sbase[b];
  int size = sizes[b]; if(size > CAP) size = CAP;

  const int2* src = part + (size_t)b * CAP;
  for(int i = tid; i < size; i += 256){
    int2 p = src[i];
    stag[i] = p;
    atomicAdd(&hist[(((unsigned)p.x) >> 16) & 255], 1);
  }
  __syncthreads();
  rowbase[tid] = block_excl_scan(hist[tid], tid, wsA);  // contains a sync
  __syncthreads();
  int grow = b * 256 + tid;
  if(grow <= n) offs[grow] = base_b + rowbase[tid];     // offs[n]=E falls out naturally
  cursor[tid] = rowbase[tid];
  __syncthreads();
  for(int i = tid; i < size; i += 256){
    int2 p = stag[i];
    int rlo = (((unsigned)p.x) >> 16) & 255;
    int pos = atomicAdd(&cursor[rlo], 1);
    int2 o; o.x = p.x & 0xFFFF; o.y = p.y;              // (s, w)
    epk[base_b + pos] = o;
  }
}

// ---------------- fused aggregate + HypAct (ht now fp16) ----------------
__global__ __launch_bounds__(256)
void agg_act_kernel(const int* __restrict__ offs, const int2* __restrict__ epk,
                    const _Float16* __restrict__ ht, float* __restrict__ out, int n)
{
  __shared__ float tr[4][128];
  int wid = threadIdx.x >> 6;
  int row = blockIdx.x * 4 + wid;
  if(row >= n) return;
  int lane = threadIdx.x & 63;
  int g = lane >> 4, i = lane & 15;
  int beg = offs[row], end = offs[row + 1];

  float acc[8] = {0.f,0.f,0.f,0.f,0.f,0.f,0.f,0.f};
  for(int j = beg; j < end; j += 64){
    int m = end - j; if(m > 64) m = 64;
    int sv = 0; float wv = 0.f;
    if(lane < m){ int2 p = epk[j + lane]; sv = p.x; wv = __int_as_float(p.y); }
    int iters = (m + 3) >> 2;
    int it = 0;
    for(; it + 1 < iters; it += 2){
      int t0 = it*4 + g, t1 = t0 + 4;
      float w0 = __shfl(wv, t0);
      int   s0 = __shfl(sv, t0);
      float w1 = (t1 < m) ? __shfl(wv, t1) : 0.f;
      int   s1 = (t1 < m) ? __shfl(sv, t1) : s0;
      halfx8 v0 = *(const halfx8*)(ht + (size_t)s0 * 128 + i * 8);
      halfx8 v1 = *(const halfx8*)(ht + (size_t)s1 * 128 + i * 8);
#pragma unroll
      for(int k = 0; k < 8; k++) acc[k] = fmaf(w0, (float)v0[k], acc[k]);
#pragma unroll
      for(int k = 0; k < 8; k++) acc[k] = fmaf(w1, (float)v1[k], acc[k]);
    }
    if(it < iters){
      int t0 = it*4 + g;
      float w0 = (t0 < m) ? __shfl(wv, t0) : 0.f;
      int   s0 = (t0 < m) ? __shfl(sv, t0) : __shfl(sv, 0);
      halfx8 v0 = *(const halfx8*)(ht + (size_t)s0 * 128 + i * 8);
#pragma unroll
      for(int k = 0; k < 8; k++) acc[k] = fmaf(w0, (float)v0[k], acc[k]);
    }
  }
#pragma unroll
  for(int k = 0; k < 8; k++){
    acc[k] += __shfl_xor(acc[k], 16);
    acc[k] += __shfl_xor(acc[k], 32);
  }

  float u2p = 0.f;
#pragma unroll
  for(int k = 0; k < 8; k++) u2p = fmaf(acc[k], acc[k], u2p);
  u2p += __shfl_xor(u2p, 1); u2p += __shfl_xor(u2p, 2);
  u2p += __shfl_xor(u2p, 4); u2p += __shfl_xor(u2p, 8);
  float un = fmaxf(sqrtf(u2p), MINN);
  float te = tanhf(un);
  float se = te / un;
  float gn = fmaxf(te, MINN);
  float hn = gn;
  if(gn > MAXN){ se *= MAXN/gn; hn = MAXN; }
  float la = artanh_(hn) / hn * se;
  float l[8];
  float r2p = 0.f;
#pragma unroll
  for(int k = 0; k < 8; k++){ l[k] = fmaxf(la*acc[k], 0.f); r2p = fmaf(l[k], l[k], r2p); }
  r2p += __shfl_xor(r2p, 1); r2p += __shfl_xor(r2p, 2);
  r2p += __shfl_xor(r2p, 4); r2p += __shfl_xor(r2p, 8);
  float rn = fmaxf(sqrtf(r2p), MINN);
  float t2 = tanhf(rn);
  float s2 = t2 / rn;
  float on = fmaxf(t2, MINN);
  if(on > MAXN) s2 *= MAXN/on;

  if(g == 0){
#pragma unroll
    for(int k = 0; k < 8; k++) tr[wid][k*16 + i] = s2 * l[k];
  }
  float2 o = *(float2*)&tr[wid][lane * 2];
  *(float2*)(out + (size_t)row * 128 + lane * 2) = o;
}

extern "C" void kernel_launch(void* const* d_in, const int* in_sizes, int n_in,
                              void* d_out, int out_size, void* d_ws, size_t ws_size,
                              hipStream_t stream)
{
  const float* x    = (const float*)d_in[0];
  const int*   adj  = (const int*)  d_in[1];
  const float* w    = (const float*)d_in[2];
  const float* W    = (const float*)d_in[3];
  const float* bias = (const float*)d_in[4];
  const int n = in_sizes[0] / 128;   // 50000
  const int E = in_sizes[2];         // 800000

  float* out     = (float*)d_out;
  float* adj_out = out + (size_t)n * 128;

  char* ws = (char*)d_ws;
  _Float16* ht   = (_Float16*)ws;  ws += (size_t)n * 128 * sizeof(_Float16);   // 12.8 MB (8B-aligned)
  int2*  part    = (int2*)ws;      ws += (size_t)256 * CAP * sizeof(int2);     // 10.5 MB
  int2*  epk     = (int2*)ws;      ws += (size_t)E * sizeof(int2);             // 6.4 MB
  int*   offs    = (int*)ws;       ws += (size_t)(n + 1) * sizeof(int);
  int*   bucketSize = (int*)ws;

  const int nbuck = (n + 255) / 256;   // 196

  hipMemsetAsync(bucketSize, 0, 256 * sizeof(int), stream);
  stageA_kernel<<<(n + 63) / 64, 256, 0, stream>>>(x, W, bias, ht, n);
  passA_kernel<<<(E + 4095) / 4096, 256, 0, stream>>>(adj, w, adj_out, bucketSize, part, E);
  passB_kernel<<<nbuck, 256, 0, stream>>>(bucketSize, part, epk, offs, n);
  agg_act_kernel<<<(n + 3) / 4, 256, 0, stream>>>(offs, epk, ht, out, n);
}

// Round 6
// 181.656 us; speedup vs baseline: 8.6049x; 1.0458x over previous
//
#include <hip/hip_runtime.h>
#include <math.h>

#define MAXN 0.996f
#define MINN 1e-15f
#define CAP  5120          // per-bucket staging capacity (mean 4096, sd ~64)

typedef __bf16   bf16x8  __attribute__((ext_vector_type(8)));
typedef _Float16 halfx8  __attribute__((ext_vector_type(8)));
typedef _Float16 half2_t __attribute__((ext_vector_type(2)));
typedef float    floatx4 __attribute__((ext_vector_type(4)));

__device__ __forceinline__ float wsum(float v){
  v += __shfl_xor(v, 32);
  v += __shfl_xor(v, 16);
  v += __shfl_xor(v, 8);
  v += __shfl_xor(v, 4);
  v += __shfl_xor(v, 2);
  v += __shfl_xor(v, 1);
  return v;
}

__device__ __forceinline__ float artanh_(float v){
  v = fminf(fmaxf(v, -1.f + 1e-7f), 1.f - 1e-7f);
  return 0.5f * (log1pf(v) - log1pf(-v));
}

// block-wide (256 thr) exclusive scan; wsums = LDS[4]; contains one __syncthreads
__device__ __forceinline__ int block_excl_scan(int v, int tid, int* wsums){
  int lane = tid & 63, wid = tid >> 6;
  int iv = v;
#pragma unroll
  for(int o = 1; o < 64; o <<= 1){
    int t = __shfl_up(iv, o);
    if(lane >= o) iv += t;
  }
  if(lane == 63) wsums[wid] = iv;
  __syncthreads();
  int wbase = 0;
  for(int k = 0; k < wid; k++) wbase += wsums[k];
  return wbase + iv - v;
}

// ---------------- Stage A: plain bf16 MFMA (r3-proven accuracy), fp16 permuted ht out
__global__ __launch_bounds__(256)
void stageA_kernel(const float* __restrict__ x, const float* __restrict__ W,
                   const float* __restrict__ bias, _Float16* __restrict__ ht, int n)
{
  __shared__ __bf16 Wh[128 * 128];   // 32 KB

  for(int g = threadIdx.x; g < 2048; g += 256){
    int nr = g >> 4, k16 = g & 15;
    const float* wp = W + nr * 128 + k16 * 8;
    float4 a = *(const float4*)wp;
    float4 b = *(const float4*)(wp + 4);
    bf16x8 h;
    h[0]=(__bf16)a.x; h[1]=(__bf16)a.y; h[2]=(__bf16)a.z; h[3]=(__bf16)a.w;
    h[4]=(__bf16)b.x; h[5]=(__bf16)b.y; h[6]=(__bf16)b.z; h[7]=(__bf16)b.w;
    *(bf16x8*)&Wh[nr * 128 + ((k16 ^ (nr & 15)) << 3)] = h;
  }
  __syncthreads();

  const int lane = threadIdx.x & 63;
  const int wid  = threadIdx.x >> 6;
  const int q    = lane >> 4;
  const int n15  = lane & 15;

  float b0 = bias[lane], b1 = bias[lane + 64];
  float bn = fmaxf(sqrtf(wsum(b0*b0 + b1*b1)), MINN);
  float sb = tanhf(bn) / bn;
  float hb0 = sb*b0, hb1 = sb*b1;
  float hnn = fmaxf(sqrtf(wsum(hb0*hb0 + hb1*hb1)), MINN);
  if(hnn > MAXN){ float f = MAXN/hnn; hb0 *= f; hb1 *= f; }
  const float y2 = wsum(hb0*hb0 + hb1*hb1);
  float hbv[8];
#pragma unroll
  for(int t = 0; t < 4; t++) hbv[t] = __shfl(hb0, t*16 + n15);
#pragma unroll
  for(int t = 4; t < 8; t++) hbv[t] = __shfl(hb1, (t-4)*16 + n15);

  const int M0 = blockIdx.x * 64 + wid * 16;
  if(M0 >= n) return;

  floatx4 acc[8];
#pragma unroll
  for(int t = 0; t < 8; t++) acc[t] = (floatx4){0.f,0.f,0.f,0.f};

  float x2p = 0.f;
  int m = M0 + n15; if(m > n - 1) m = n - 1;
#pragma unroll
  for(int kk = 0; kk < 4; kk++){
    const float* xp = x + (size_t)m * 128 + kk * 32 + q * 8;
    float4 xa = *(const float4*)xp;
    float4 xb = *(const float4*)(xp + 4);
    x2p += xa.x*xa.x + xa.y*xa.y + xa.z*xa.z + xa.w*xa.w
         + xb.x*xb.x + xb.y*xb.y + xb.z*xb.z + xb.w*xb.w;
    bf16x8 a;
    a[0]=(__bf16)xa.x; a[1]=(__bf16)xa.y; a[2]=(__bf16)xa.z; a[3]=(__bf16)xa.w;
    a[4]=(__bf16)xb.x; a[5]=(__bf16)xb.y; a[6]=(__bf16)xb.z; a[7]=(__bf16)xb.w;
    int k16 = kk * 4 + q;
#pragma unroll
    for(int t = 0; t < 8; t++){
      bf16x8 b = *(bf16x8*)&Wh[(t*16 + n15) * 128 + ((k16 ^ n15) << 3)];
      acc[t] = __builtin_amdgcn_mfma_f32_16x16x32_bf16(a, b, acc[t], 0, 0, 0);
    }
  }
  x2p += __shfl_xor(x2p, 16);
  x2p += __shfl_xor(x2p, 32);

#pragma unroll
  for(int i = 0; i < 4; i++){
    const int row  = q * 4 + i;
    const int grow = M0 + row;
    float mp = 0.f, dp = 0.f;
#pragma unroll
    for(int t = 0; t < 8; t++){ float v = acc[t][i]; mp = fmaf(v, v, mp); dp = fmaf(v, hbv[t], dp); }
    mp += __shfl_xor(mp, 1); mp += __shfl_xor(mp, 2); mp += __shfl_xor(mp, 4); mp += __shfl_xor(mp, 8);
    dp += __shfl_xor(dp, 1); dp += __shfl_xor(dp, 2); dp += __shfl_xor(dp, 4); dp += __shfl_xor(dp, 8);
    float X2  = __shfl(x2p, row);
    float mxn = fmaxf(sqrtf(mp), MINN);
    float xn  = fmaxf(sqrtf(X2), MINN);
    float tt  = tanhf(mxn / xn * artanh_(xn));
    float s1  = tt / mxn;
    float rn  = fmaxf(tt, MINN);
    if(rn > MAXN) s1 *= MAXN / rn;
    float xy    = s1 * dp;
    float r2    = s1 * s1 * mp;
    float alpha = 1.f + 2.f*xy + y2;
    float beta  = 1.f - r2;
    float inv   = 1.f / fmaxf(1.f + 2.f*xy + r2*y2, MINN);
    float as1   = alpha * s1;
    float uv[8];
    float u2p = 0.f;
#pragma unroll
    for(int t = 0; t < 8; t++){
      uv[t] = (as1 * acc[t][i] + beta * hbv[t]) * inv;
      u2p = fmaf(uv[t], uv[t], u2p);
    }
    u2p += __shfl_xor(u2p, 1); u2p += __shfl_xor(u2p, 2); u2p += __shfl_xor(u2p, 4); u2p += __shfl_xor(u2p, 8);
    float un = fmaxf(sqrtf(u2p), MINN);
    float sc = 1.f, hn = un;
    if(un > MAXN){ sc = MAXN/un; hn = MAXN; }
    float lt = artanh_(hn) / hn * sc;
    if(grow < n){
      halfx8 f;
#pragma unroll
      for(int t = 0; t < 8; t++) f[t] = (_Float16)(lt * uv[t]);
      *(halfx8*)(ht + (size_t)grow * 128 + n15 * 8) = f;
    }
  }
}

// ---------------- Pass A: bucket partition (b = r>>8) + adj->float copy ----------------
__global__ __launch_bounds__(256)
void passA_kernel(const int* __restrict__ adj, const float* __restrict__ w,
                  float* __restrict__ adj_out, int* __restrict__ bucketSize,
                  int2* __restrict__ part, int E)
{
  __shared__ int hist[4][256];   // per-wave histograms
  __shared__ int wcur[4][256];   // per-wave cursors
  __shared__ int lbase[256];
  __shared__ int gbase[256];
  __shared__ int wsA[4];
  __shared__ int2 stag[4096];

  const int tid = threadIdx.x;
  const int wv  = tid >> 6;
#pragma unroll
  for(int k = 0; k < 4; k++) hist[k][tid] = 0;
  __syncthreads();

  const int e0 = blockIdx.x * 4096;
  int p0r[16], p1r[16];
#pragma unroll
  for(int k = 0; k < 16; k++){
    int e = e0 + k*256 + tid;
    if(e < E){
      int s = adj[e];
      int r = adj[e + E];
      float we = w[e];
      adj_out[e]     = (float)s;
      adj_out[e + E] = (float)r;
      int b = r >> 8;
      p0r[k] = s | ((r & 255) << 16) | (b << 24);
      p1r[k] = __float_as_int(we);
      atomicAdd(&hist[wv][b], 1);
    }
  }
  __syncthreads();
  int cb = hist[0][tid] + hist[1][tid] + hist[2][tid] + hist[3][tid];
  int lb = block_excl_scan(cb, tid, wsA);   // contains a sync
  lbase[tid]   = lb;
  wcur[0][tid] = lb;
  wcur[1][tid] = lb + hist[0][tid];
  wcur[2][tid] = lb + hist[0][tid] + hist[1][tid];
  wcur[3][tid] = lb + hist[0][tid] + hist[1][tid] + hist[2][tid];
  gbase[tid] = cb ? atomicAdd(&bucketSize[tid], cb) : 0;
  __syncthreads();
#pragma unroll
  for(int k = 0; k < 16; k++){
    int e = e0 + k*256 + tid;
    if(e < E){
      int b = ((unsigned)p0r[k]) >> 24;
      int pos = atomicAdd(&wcur[wv][b], 1);
      stag[pos] = make_int2(p0r[k], p1r[k]);
    }
  }
  __syncthreads();
  int total = (e0 + 4096 <= E) ? 4096 : (E - e0);
  for(int i = tid; i < total; i += 256){
    int2 p = stag[i];
    int b = ((unsigned)p.x) >> 24;
    int loc = gbase[b] + (i - lbase[b]);
    if(loc < CAP) part[(size_t)b * CAP + loc] = p;
  }
}

// ---------------- Pass B: per-bucket local CSR; writes offs + packed 4B epk ----------------
__global__ __launch_bounds__(256)
void passB_kernel(const int* __restrict__ bucketSize, const int2* __restrict__ part,
                  unsigned* __restrict__ epk, int* __restrict__ offs, int n)
{
  __shared__ int sizes[256];
  __shared__ int hist[256];
  __shared__ int rowbase[256];
  __shared__ int cursor[256];
  __shared__ int wsA[4];
  __shared__ int2 stag[CAP];

  const int tid = threadIdx.x;
  const int b   = blockIdx.x;
  sizes[tid] = bucketSize[tid];
  hist[tid]  = 0;
  __syncthreads();
  int sb = block_excl_scan(sizes[tid], tid, wsA);   // contains a sync
  __shared__ int base_sh;
  if(tid == b) base_sh = sb;
  __syncthreads();
  const int base_b = base_sh;
  int size = sizes[b]; if(size > CAP) size = CAP;

  const int2* src = part + (size_t)b * CAP;
  for(int i = tid; i < size; i += 256){
    int2 p = src[i];
    stag[i] = p;
    atomicAdd(&hist[(((unsigned)p.x) >> 16) & 255], 1);
  }
  __syncthreads();
  int rb = block_excl_scan(hist[tid], tid, wsA);    // contains a sync
  rowbase[tid] = rb;
  int grow = b * 256 + tid;
  if(grow <= n) offs[grow] = base_b + rb;
  cursor[tid] = rb;
  __syncthreads();
  for(int i = tid; i < size; i += 256){
    int2 p = stag[i];
    int rlo = (((unsigned)p.x) >> 16) & 255;
    int pos = atomicAdd(&cursor[rlo], 1);
    unsigned wh = (unsigned)__builtin_bit_cast(unsigned short,
                    (_Float16)__builtin_bit_cast(float, p.y));
    epk[base_b + pos] = (unsigned)(p.x & 0xFFFF) | (wh << 16);
  }
}

// ---------------- fused aggregate + HypAct ----------------
// One wave per row, 16 lanes per edge-group; epk word loaded by all 16 lanes
// (same-address broadcast), weight dup via v_perm, inner product via v_pk_fma_f16.
__global__ __launch_bounds__(256)
void agg_act_kernel(const int* __restrict__ offs, const unsigned* __restrict__ epk,
                    const _Float16* __restrict__ ht, float* __restrict__ out, int n)
{
  __shared__ float tr[4][128];
  int wid = threadIdx.x >> 6;
  int row = blockIdx.x * 4 + wid;
  if(row >= n) return;
  int lane = threadIdx.x & 63;
  int g = lane >> 4, i = lane & 15;
  int beg = offs[row];
  int m   = offs[row + 1] - beg;
  const unsigned* ep = epk + beg;
  const char* htb = (const char*)ht;
  const int ioff = i << 4;

  half2_t acc2[4];
#pragma unroll
  for(int k = 0; k < 4; k++) acc2[k] = (half2_t){(_Float16)0.f, (_Float16)0.f};

#define EDGE(pk) { \
    int s_ = (int)((pk) & 0xFFFFu); \
    half2_t w2_ = __builtin_bit_cast(half2_t, __builtin_amdgcn_perm(pk, pk, 0x03020302u)); \
    int4 q_ = *(const int4*)(htb + ((s_ << 8) | ioff)); \
    acc2[0] = __builtin_bit_cast(half2_t, q_.x) * w2_ + acc2[0]; \
    acc2[1] = __builtin_bit_cast(half2_t, q_.y) * w2_ + acc2[1]; \
    acc2[2] = __builtin_bit_cast(half2_t, q_.z) * w2_ + acc2[2]; \
    acc2[3] = __builtin_bit_cast(half2_t, q_.w) * w2_ + acc2[3]; \
  }

  int iters = (m + 3) >> 2;
  int it = 0;
  for(; it + 1 < iters; it += 2){
    int t0 = it*4 + g;            // t0 <= m-2 always
    int t1 = t0 + 4;
    unsigned pk0 = ep[t0];
    int tc1 = (t1 < m) ? t1 : (m - 1);
    unsigned pk1 = ep[tc1];
    if(t1 >= m) pk1 &= 0xFFFFu;   // zero fp16 weight
    EDGE(pk0);
    EDGE(pk1);
  }
  if(it < iters){
    int t0 = it*4 + g;
    int tc0 = (t0 < m) ? t0 : (m - 1);
    unsigned pk0 = ep[tc0];
    if(t0 >= m) pk0 &= 0xFFFFu;
    EDGE(pk0);
  }
#undef EDGE

  float acc[8];
#pragma unroll
  for(int k = 0; k < 4; k++){
    acc[2*k]   = (float)acc2[k][0];
    acc[2*k+1] = (float)acc2[k][1];
  }
#pragma unroll
  for(int k = 0; k < 8; k++){
    acc[k] += __shfl_xor(acc[k], 16);
    acc[k] += __shfl_xor(acc[k], 32);
  }

  float u2p = 0.f;
#pragma unroll
  for(int k = 0; k < 8; k++) u2p = fmaf(acc[k], acc[k], u2p);
  u2p += __shfl_xor(u2p, 1); u2p += __shfl_xor(u2p, 2);
  u2p += __shfl_xor(u2p, 4); u2p += __shfl_xor(u2p, 8);
  float un = fmaxf(sqrtf(u2p), MINN);
  float te = tanhf(un);
  float se = te / un;
  float gn = fmaxf(te, MINN);
  float hn = gn;
  if(gn > MAXN){ se *= MAXN/gn; hn = MAXN; }
  float la = artanh_(hn) / hn * se;
  float l[8];
  float r2p = 0.f;
#pragma unroll
  for(int k = 0; k < 8; k++){ l[k] = fmaxf(la*acc[k], 0.f); r2p = fmaf(l[k], l[k], r2p); }
  r2p += __shfl_xor(r2p, 1); r2p += __shfl_xor(r2p, 2);
  r2p += __shfl_xor(r2p, 4); r2p += __shfl_xor(r2p, 8);
  float rn = fmaxf(sqrtf(r2p), MINN);
  float t2 = tanhf(rn);
  float s2 = t2 / rn;
  float on = fmaxf(t2, MINN);
  if(on > MAXN) s2 *= MAXN/on;

  if(g == 0){
#pragma unroll
    for(int k = 0; k < 8; k++) tr[wid][k*16 + i] = s2 * l[k];
  }
  float2 o = *(float2*)&tr[wid][lane * 2];
  *(float2*)(out + (size_t)row * 128 + lane * 2) = o;
}

extern "C" void kernel_launch(void* const* d_in, const int* in_sizes, int n_in,
                              void* d_out, int out_size, void* d_ws, size_t ws_size,
                              hipStream_t stream)
{
  const float* x    = (const float*)d_in[0];
  const int*   adj  = (const int*)  d_in[1];
  const float* w    = (const float*)d_in[2];
  const float* W    = (const float*)d_in[3];
  const float* bias = (const float*)d_in[4];
  const int n = in_sizes[0] / 128;   // 50000
  const int E = in_sizes[2];         // 800000

  float* out     = (float*)d_out;
  float* adj_out = out + (size_t)n * 128;

  char* ws = (char*)d_ws;
  _Float16* ht   = (_Float16*)ws;  ws += (size_t)n * 128 * sizeof(_Float16);   // 12.8 MB
  int2*  part    = (int2*)ws;      ws += (size_t)256 * CAP * sizeof(int2);     // 10.5 MB
  unsigned* epk  = (unsigned*)ws;  ws += (size_t)E * sizeof(unsigned);         // 3.2 MB
  int*   offs    = (int*)ws;       ws += (size_t)(n + 1) * sizeof(int);
  int*   bucketSize = (int*)ws;

  const int nbuck = (n + 255) / 256;   // 196

  hipMemsetAsync(bucketSize, 0, 256 * sizeof(int), stream);
  stageA_kernel<<<(n + 63) / 64, 256, 0, stream>>>(x, W, bias, ht, n);
  passA_kernel<<<(E + 4095) / 4096, 256, 0, stream>>>(adj, w, adj_out, bucketSize, part, E);
  passB_kernel<<<nbuck, 256, 0, stream>>>(bucketSize, part, epk, offs, n);
  agg_act_kernel<<<(n + 3) / 4, 256, 0, stream>>>(offs, epk, ht, out, n);
}

// Round 7
// 160.697 us; speedup vs baseline: 9.7272x; 1.1304x over previous
//
#include <hip/hip_runtime.h>
#include <math.h>

#define MAXN 0.996f
#define MINN 1e-15f
#define CAP  5120          // per-bucket staging capacity (mean 4096, sd ~64)

typedef __bf16   bf16x8  __attribute__((ext_vector_type(8)));
typedef _Float16 halfx8  __attribute__((ext_vector_type(8)));
typedef _Float16 half2_t __attribute__((ext_vector_type(2)));
typedef float    floatx4 __attribute__((ext_vector_type(4)));

__device__ __forceinline__ float wsum(float v){
  v += __shfl_xor(v, 32);
  v += __shfl_xor(v, 16);
  v += __shfl_xor(v, 8);
  v += __shfl_xor(v, 4);
  v += __shfl_xor(v, 2);
  v += __shfl_xor(v, 1);
  return v;
}

__device__ __forceinline__ float artanh_(float v){
  v = fminf(fmaxf(v, -1.f + 1e-7f), 1.f - 1e-7f);
  return 0.5f * (log1pf(v) - log1pf(-v));
}

// block-wide (256 thr) exclusive scan; wsums = LDS[4]; contains one __syncthreads
__device__ __forceinline__ int block_excl_scan(int v, int tid, int* wsums){
  int lane = tid & 63, wid = tid >> 6;
  int iv = v;
#pragma unroll
  for(int o = 1; o < 64; o <<= 1){
    int t = __shfl_up(iv, o);
    if(lane >= o) iv += t;
  }
  if(lane == 63) wsums[wid] = iv;
  __syncthreads();
  int wbase = 0;
  for(int k = 0; k < wid; k++) wbase += wsums[k];
  return wbase + iv - v;
}

// =================== FUSED: passA (blocks 0..nA-1) + stageA (blocks nA..) ===================
// LDS union: passA needs ~42.1 KB, stageA needs ~33.3 KB.
__global__ __launch_bounds__(256)
void fusedA_kernel(const float* __restrict__ x, const float* __restrict__ W,
                   const float* __restrict__ bias, _Float16* __restrict__ ht, int n,
                   const int* __restrict__ adj, const float* __restrict__ w,
                   float* __restrict__ adj_out, int* __restrict__ bucketSize,
                   int2* __restrict__ part, int E, int nA)
{
  __shared__ __align__(16) char smem[43264];
  const int tid = threadIdx.x;

  if(blockIdx.x < nA){
    // ---------------- passA: bucket partition (b = r>>8) + adj->float copy ----------------
    int* hist  = (int*)smem;            // 4 KB (4 waves x 256)
    int* wcur  = (int*)(smem + 4096);   // 4 KB
    int* lbase = (int*)(smem + 8192);   // 1 KB
    int* gbase = (int*)(smem + 9216);   // 1 KB
    int* wsA   = (int*)(smem + 10240);  // 16 B
    int2* stag = (int2*)(smem + 10256); // 32 KB

    const int wv = tid >> 6;
#pragma unroll
    for(int k = 0; k < 4; k++) hist[k*256 + tid] = 0;
    __syncthreads();

    const int e0 = blockIdx.x * 4096;
    int p0r[16], p1r[16];
#pragma unroll
    for(int k = 0; k < 16; k++){
      int e = e0 + k*256 + tid;
      if(e < E){
        int s = adj[e];
        int r = adj[e + E];
        float we = w[e];
        adj_out[e]     = (float)s;
        adj_out[e + E] = (float)r;
        int b = r >> 8;
        p0r[k] = s | ((r & 255) << 16) | (b << 24);
        p1r[k] = __float_as_int(we);
        atomicAdd(&hist[wv*256 + b], 1);
      }
    }
    __syncthreads();
    int h0 = hist[0*256+tid], h1 = hist[1*256+tid], h2 = hist[2*256+tid], h3 = hist[3*256+tid];
    int cb = h0 + h1 + h2 + h3;
    int lb = block_excl_scan(cb, tid, wsA);   // contains a sync
    lbase[tid]      = lb;
    wcur[0*256+tid] = lb;
    wcur[1*256+tid] = lb + h0;
    wcur[2*256+tid] = lb + h0 + h1;
    wcur[3*256+tid] = lb + h0 + h1 + h2;
    gbase[tid] = cb ? atomicAdd(&bucketSize[tid], cb) : 0;
    __syncthreads();
#pragma unroll
    for(int k = 0; k < 16; k++){
      int e = e0 + k*256 + tid;
      if(e < E){
        int b = ((unsigned)p0r[k]) >> 24;
        int pos = atomicAdd(&wcur[wv*256 + b], 1);
        stag[pos] = make_int2(p0r[k], p1r[k]);
      }
    }
    __syncthreads();
    int total = (e0 + 4096 <= E) ? 4096 : (E - e0);
    for(int i = tid; i < total; i += 256){
      int2 p = stag[i];
      int b = ((unsigned)p.x) >> 24;
      int loc = gbase[b] + (i - lbase[b]);
      if(loc < CAP) part[(size_t)b * CAP + loc] = p;
    }
    return;
  }

  // ---------------- stageA: ht = logmap0(proj(mobius_add(proj(mobius_matvec(W,x)), hb)))
  __bf16* Wh   = (__bf16*)smem;            // 32 KB
  float* hb_sh = (float*)(smem + 32768);   // 512 B
  float* y2_sh = (float*)(smem + 33280);   // 4 B

  for(int g = tid; g < 2048; g += 256){
    int nr = g >> 4, k16 = g & 15;
    const float* wp = W + nr * 128 + k16 * 8;
    float4 a = *(const float4*)wp;
    float4 b = *(const float4*)(wp + 4);
    bf16x8 h;
    h[0]=(__bf16)a.x; h[1]=(__bf16)a.y; h[2]=(__bf16)a.z; h[3]=(__bf16)a.w;
    h[4]=(__bf16)b.x; h[5]=(__bf16)b.y; h[6]=(__bf16)b.z; h[7]=(__bf16)b.w;
    *(bf16x8*)&Wh[nr * 128 + ((k16 ^ (nr & 15)) << 3)] = h;
  }
  if(tid < 64){
    int l = tid;
    float b0 = bias[l], b1 = bias[l + 64];
    float bn = fmaxf(sqrtf(wsum(b0*b0 + b1*b1)), MINN);
    float sb = tanhf(bn) / bn;
    float hb0 = sb*b0, hb1 = sb*b1;
    float hnn = fmaxf(sqrtf(wsum(hb0*hb0 + hb1*hb1)), MINN);
    if(hnn > MAXN){ float f = MAXN/hnn; hb0 *= f; hb1 *= f; }
    float y2 = wsum(hb0*hb0 + hb1*hb1);
    hb_sh[l] = hb0; hb_sh[l + 64] = hb1;
    if(l == 0) *y2_sh = y2;
  }
  __syncthreads();

  const int lane = tid & 63;
  const int wid  = tid >> 6;
  const int q    = lane >> 4;
  const int n15  = lane & 15;

  const int M0 = (blockIdx.x - nA) * 64 + wid * 16;
  if(M0 >= n) return;

  float hbv[8];
#pragma unroll
  for(int t = 0; t < 8; t++) hbv[t] = hb_sh[t*16 + n15];
  const float y2 = *y2_sh;

  floatx4 acc[8];
#pragma unroll
  for(int t = 0; t < 8; t++) acc[t] = (floatx4){0.f,0.f,0.f,0.f};

  float x2p = 0.f;
  int m = M0 + n15; if(m > n - 1) m = n - 1;
#pragma unroll
  for(int kk = 0; kk < 4; kk++){
    const float* xp = x + (size_t)m * 128 + kk * 32 + q * 8;
    float4 xa = *(const float4*)xp;
    float4 xb = *(const float4*)(xp + 4);
    x2p += xa.x*xa.x + xa.y*xa.y + xa.z*xa.z + xa.w*xa.w
         + xb.x*xb.x + xb.y*xb.y + xb.z*xb.z + xb.w*xb.w;
    bf16x8 a;
    a[0]=(__bf16)xa.x; a[1]=(__bf16)xa.y; a[2]=(__bf16)xa.z; a[3]=(__bf16)xa.w;
    a[4]=(__bf16)xb.x; a[5]=(__bf16)xb.y; a[6]=(__bf16)xb.z; a[7]=(__bf16)xb.w;
    int k16 = kk * 4 + q;
#pragma unroll
    for(int t = 0; t < 8; t++){
      bf16x8 b = *(bf16x8*)&Wh[(t*16 + n15) * 128 + ((k16 ^ n15) << 3)];
      acc[t] = __builtin_amdgcn_mfma_f32_16x16x32_bf16(a, b, acc[t], 0, 0, 0);
    }
  }
  // lane (q,n15) -> row n15's ||x||^2 after summing over quads
  x2p += __shfl_xor(x2p, 16);
  x2p += __shfl_xor(x2p, 32);

  // per-i reductions: mp_i = ||mx_row||^2, dp_i = mx_row . hb  (valid on quad's 16 lanes)
  float mp[4], dp[4];
#pragma unroll
  for(int i = 0; i < 4; i++){
    float mpi = 0.f, dpi = 0.f;
#pragma unroll
    for(int t = 0; t < 8; t++){ float v = acc[t][i]; mpi = fmaf(v, v, mpi); dpi = fmaf(v, hbv[t], dpi); }
    mpi += __shfl_xor(mpi, 1); mpi += __shfl_xor(mpi, 2); mpi += __shfl_xor(mpi, 4); mpi += __shfl_xor(mpi, 8);
    dpi += __shfl_xor(dpi, 1); dpi += __shfl_xor(dpi, 2); dpi += __shfl_xor(dpi, 4); dpi += __shfl_xor(dpi, 8);
    mp[i] = mpi; dp[i] = dpi;
  }

  // ---- transpose to lanes 0..15 (lane j = row j) and run the scalar chain ONCE ----
  const int li   = lane & 3;
  const int srcl = (((lane >> 2) << 4) | li) & 63;
  float selmp = li==0 ? mp[0] : li==1 ? mp[1] : li==2 ? mp[2] : mp[3];
  float seldp = li==0 ? dp[0] : li==1 ? dp[1] : li==2 ? dp[2] : dp[3];
  float tmp_mp = __shfl(selmp, srcl);
  float tmp_dp = __shfl(seldp, srcl);
  // lane j (<16): X2 of row j is x2p (keyed by n15 == j)
  float mxn = fmaxf(sqrtf(tmp_mp), MINN);
  float xn  = fmaxf(sqrtf(x2p), MINN);
  float tt  = tanhf(mxn / xn * artanh_(xn));
  float s1  = tt / mxn;
  float rn  = fmaxf(tt, MINN);
  if(rn > MAXN) s1 *= MAXN / rn;
  float xy    = s1 * tmp_dp;
  float r2    = s1 * s1 * tmp_mp;
  float alpha = 1.f + 2.f*xy + y2;
  float beta  = 1.f - r2;
  float inv   = 1.f / fmaxf(1.f + 2.f*xy + r2*y2, MINN);
  float as1   = alpha * s1;

  // ---- broadcast (as1, beta, inv) back: row q*4+i lives on lane q*4+i ----
  float as1b[4], betab[4], invb[4];
#pragma unroll
  for(int i = 0; i < 4; i++){
    int sl = ((lane >> 4) << 2) | i;
    as1b[i]  = __shfl(as1, sl);
    betab[i] = __shfl(beta, sl);
    invb[i]  = __shfl(inv, sl);
  }

  // ---- u = mobius_add result per row; u2 reductions ----
  float uv[4][8];
  float u2[4];
#pragma unroll
  for(int i = 0; i < 4; i++){
    float u2i = 0.f;
#pragma unroll
    for(int t = 0; t < 8; t++){
      float u = (as1b[i] * acc[t][i] + betab[i] * hbv[t]) * invb[i];
      uv[i][t] = u;
      u2i = fmaf(u, u, u2i);
    }
    u2i += __shfl_xor(u2i, 1); u2i += __shfl_xor(u2i, 2); u2i += __shfl_xor(u2i, 4); u2i += __shfl_xor(u2i, 8);
    u2[i] = u2i;
  }

  // ---- transpose u2, single proj+logmap0 chain, broadcast lt back ----
  float selu = li==0 ? u2[0] : li==1 ? u2[1] : li==2 ? u2[2] : u2[3];
  float tu   = __shfl(selu, srcl);
  float un = fmaxf(sqrtf(tu), MINN);
  float sc = 1.f, hn = un;
  if(un > MAXN){ sc = MAXN/un; hn = MAXN; }
  float lt = artanh_(hn) / hn * sc;

#pragma unroll
  for(int i = 0; i < 4; i++){
    int grow = M0 + q * 4 + i;
    float lti = __shfl(lt, ((lane >> 4) << 2) | i);
    if(grow < n){
      halfx8 f;
#pragma unroll
      for(int t = 0; t < 8; t++) f[t] = (_Float16)(lti * uv[i][t]);
      *(halfx8*)(ht + (size_t)grow * 128 + n15 * 8) = f;
    }
  }
}

// ---------------- Pass B: per-bucket local CSR; writes offs + packed 4B epk ----------------
__global__ __launch_bounds__(256)
void passB_kernel(const int* __restrict__ bucketSize, const int2* __restrict__ part,
                  unsigned* __restrict__ epk, int* __restrict__ offs, int n)
{
  __shared__ int sizes[256];
  __shared__ int hist[256];
  __shared__ int cursor[256];
  __shared__ int wsA[4];
  __shared__ int2 stag[CAP];

  const int tid = threadIdx.x;
  const int b   = blockIdx.x;
  sizes[tid] = bucketSize[tid];
  hist[tid]  = 0;
  __syncthreads();
  int sb = block_excl_scan(sizes[tid], tid, wsA);   // contains a sync
  __shared__ int base_sh;
  if(tid == b) base_sh = sb;
  __syncthreads();
  const int base_b = base_sh;
  int size = sizes[b]; if(size > CAP) size = CAP;

  const int2* src = part + (size_t)b * CAP;
  for(int i = tid; i < size; i += 256){
    int2 p = src[i];
    stag[i] = p;
    atomicAdd(&hist[(((unsigned)p.x) >> 16) & 255], 1);
  }
  __syncthreads();
  int rb = block_excl_scan(hist[tid], tid, wsA);    // contains a sync
  int grow = b * 256 + tid;
  if(grow <= n) offs[grow] = base_b + rb;
  cursor[tid] = rb;
  __syncthreads();
  for(int i = tid; i < size; i += 256){
    int2 p = stag[i];
    int rlo = (((unsigned)p.x) >> 16) & 255;
    int pos = atomicAdd(&cursor[rlo], 1);
    unsigned wh = (unsigned)__builtin_bit_cast(unsigned short,
                    (_Float16)__builtin_bit_cast(float, p.y));
    epk[base_b + pos] = (unsigned)(p.x & 0xFFFF) | (wh << 16);
  }
}

// ---------------- fused aggregate + HypAct ----------------
__global__ __launch_bounds__(256)
void agg_act_kernel(const int* __restrict__ offs, const unsigned* __restrict__ epk,
                    const _Float16* __restrict__ ht, float* __restrict__ out, int n)
{
  __shared__ float tr[4][128];
  int wid = threadIdx.x >> 6;
  int row = blockIdx.x * 4 + wid;
  if(row >= n) return;
  int lane = threadIdx.x & 63;
  int g = lane >> 4, i = lane & 15;
  int beg = offs[row];
  int m   = offs[row + 1] - beg;
  const unsigned* ep = epk + beg;
  const char* htb = (const char*)ht;
  const int ioff = i << 4;

  half2_t acc2[4];
#pragma unroll
  for(int k = 0; k < 4; k++) acc2[k] = (half2_t){(_Float16)0.f, (_Float16)0.f};

#define EDGE(pk) { \
    int s_ = (int)((pk) & 0xFFFFu); \
    half2_t w2_ = __builtin_bit_cast(half2_t, __builtin_amdgcn_perm(pk, pk, 0x03020302u)); \
    int4 q_ = *(const int4*)(htb + ((s_ << 8) | ioff)); \
    acc2[0] = __builtin_bit_cast(half2_t, q_.x) * w2_ + acc2[0]; \
    acc2[1] = __builtin_bit_cast(half2_t, q_.y) * w2_ + acc2[1]; \
    acc2[2] = __builtin_bit_cast(half2_t, q_.z) * w2_ + acc2[2]; \
    acc2[3] = __builtin_bit_cast(half2_t, q_.w) * w2_ + acc2[3]; \
  }

  int iters = (m + 3) >> 2;
  int it = 0;
  for(; it + 1 < iters; it += 2){
    int t0 = it*4 + g;
    int t1 = t0 + 4;
    unsigned pk0 = ep[t0];
    int tc1 = (t1 < m) ? t1 : (m - 1);
    unsigned pk1 = ep[tc1];
    if(t1 >= m) pk1 &= 0xFFFFu;
    EDGE(pk0);
    EDGE(pk1);
  }
  if(it < iters){
    int t0 = it*4 + g;
    int tc0 = (t0 < m) ? t0 : (m - 1);
    unsigned pk0 = ep[tc0];
    if(t0 >= m) pk0 &= 0xFFFFu;
    EDGE(pk0);
  }
#undef EDGE

  float acc[8];
#pragma unroll
  for(int k = 0; k < 4; k++){
    acc[2*k]   = (float)acc2[k][0];
    acc[2*k+1] = (float)acc2[k][1];
  }
#pragma unroll
  for(int k = 0; k < 8; k++){
    acc[k] += __shfl_xor(acc[k], 16);
    acc[k] += __shfl_xor(acc[k], 32);
  }

  float u2p = 0.f;
#pragma unroll
  for(int k = 0; k < 8; k++) u2p = fmaf(acc[k], acc[k], u2p);
  u2p += __shfl_xor(u2p, 1); u2p += __shfl_xor(u2p, 2);
  u2p += __shfl_xor(u2p, 4); u2p += __shfl_xor(u2p, 8);
  float un = fmaxf(sqrtf(u2p), MINN);
  float te = tanhf(un);
  float se = te / un;
  float gn = fmaxf(te, MINN);
  float hn = gn;
  if(gn > MAXN){ se *= MAXN/gn; hn = MAXN; }
  float la = artanh_(hn) / hn * se;
  float l[8];
  float r2p = 0.f;
#pragma unroll
  for(int k = 0; k < 8; k++){ l[k] = fmaxf(la*acc[k], 0.f); r2p = fmaf(l[k], l[k], r2p); }
  r2p += __shfl_xor(r2p, 1); r2p += __shfl_xor(r2p, 2);
  r2p += __shfl_xor(r2p, 4); r2p += __shfl_xor(r2p, 8);
  float rn = fmaxf(sqrtf(r2p), MINN);
  float t2 = tanhf(rn);
  float s2 = t2 / rn;
  float on = fmaxf(t2, MINN);
  if(on > MAXN) s2 *= MAXN/on;

  if(g == 0){
#pragma unroll
    for(int k = 0; k < 8; k++) tr[wid][k*16 + i] = s2 * l[k];
  }
  float2 o = *(float2*)&tr[wid][lane * 2];
  *(float2*)(out + (size_t)row * 128 + lane * 2) = o;
}

extern "C" void kernel_launch(void* const* d_in, const int* in_sizes, int n_in,
                              void* d_out, int out_size, void* d_ws, size_t ws_size,
                              hipStream_t stream)
{
  const float* x    = (const float*)d_in[0];
  const int*   adj  = (const int*)  d_in[1];
  const float* w    = (const float*)d_in[2];
  const float* W    = (const float*)d_in[3];
  const float* bias = (const float*)d_in[4];
  const int n = in_sizes[0] / 128;   // 50000
  const int E = in_sizes[2];         // 800000

  float* out     = (float*)d_out;
  float* adj_out = out + (size_t)n * 128;

  char* ws = (char*)d_ws;
  _Float16* ht   = (_Float16*)ws;  ws += (size_t)n * 128 * sizeof(_Float16);   // 12.8 MB
  int2*  part    = (int2*)ws;      ws += (size_t)256 * CAP * sizeof(int2);     // 10.5 MB
  unsigned* epk  = (unsigned*)ws;  ws += (size_t)E * sizeof(unsigned);         // 3.2 MB
  int*   offs    = (int*)ws;       ws += (size_t)(n + 1) * sizeof(int);
  int*   bucketSize = (int*)ws;

  const int nA = (E + 4095) / 4096;   // 196 passA blocks
  const int nS = (n + 63) / 64;       // 782 stageA blocks

  hipMemsetAsync(bucketSize, 0, 256 * sizeof(int), stream);
  fusedA_kernel<<<nA + nS, 256, 0, stream>>>(x, W, bias, ht, n,
                                             adj, w, adj_out, bucketSize, part, E, nA);
  passB_kernel<<<(n + 255) / 256, 256, 0, stream>>>(bucketSize, part, epk, offs, n);
  agg_act_kernel<<<(n + 3) / 4, 256, 0, stream>>>(offs, epk, ht, out, n);
}

// Round 8
// 153.782 us; speedup vs baseline: 10.1646x; 1.0450x over previous
//
#include <hip/hip_runtime.h>
#include <math.h>

#define MAXN 0.996f
#define MINN 1e-15f
#define CAP  5120          // per-bucket staging capacity (mean 4096, sd ~64)

typedef __bf16   bf16x8  __attribute__((ext_vector_type(8)));
typedef _Float16 halfx8  __attribute__((ext_vector_type(8)));
typedef _Float16 half2_t __attribute__((ext_vector_type(2)));
typedef float    floatx4 __attribute__((ext_vector_type(4)));

__device__ __forceinline__ float wsum(float v){
  v += __shfl_xor(v, 32);
  v += __shfl_xor(v, 16);
  v += __shfl_xor(v, 8);
  v += __shfl_xor(v, 4);
  v += __shfl_xor(v, 2);
  v += __shfl_xor(v, 1);
  return v;
}

__device__ __forceinline__ float artanh_(float v){
  v = fminf(fmaxf(v, -1.f + 1e-7f), 1.f - 1e-7f);
  return 0.5f * (log1pf(v) - log1pf(-v));
}

// block-wide (256 thr) exclusive scan; wsums = LDS[4]; contains one __syncthreads
__device__ __forceinline__ int block_excl_scan(int v, int tid, int* wsums){
  int lane = tid & 63, wid = tid >> 6;
  int iv = v;
#pragma unroll
  for(int o = 1; o < 64; o <<= 1){
    int t = __shfl_up(iv, o);
    if(lane >= o) iv += t;
  }
  if(lane == 63) wsums[wid] = iv;
  __syncthreads();
  int wbase = 0;
  for(int k = 0; k < wid; k++) wbase += wsums[k];
  return wbase + iv - v;
}

// =================== FUSED: passA (blocks 0..nA-1) + stageA (blocks nA..) ===================
__global__ __launch_bounds__(256)
void fusedA_kernel(const float* __restrict__ x, const float* __restrict__ W,
                   const float* __restrict__ bias, _Float16* __restrict__ ht, int n,
                   const int* __restrict__ adj, const float* __restrict__ w,
                   float* __restrict__ adj_out, int* __restrict__ bucketSize,
                   int2* __restrict__ part, int E, int nA)
{
  __shared__ __align__(16) char smem[43264];
  const int tid = threadIdx.x;

  if(blockIdx.x < nA){
    // ---------------- passA: bucket partition (b = r>>8) + adj->float copy ----------------
    int* hist  = (int*)smem;            // 4 KB (4 waves x 256)
    int* wcur  = (int*)(smem + 4096);   // 4 KB
    int* lbase = (int*)(smem + 8192);   // 1 KB
    int* gbase = (int*)(smem + 9216);   // 1 KB
    int* wsA   = (int*)(smem + 10240);  // 16 B
    int2* stag = (int2*)(smem + 10256); // 32 KB

    const int wv = tid >> 6;
#pragma unroll
    for(int k = 0; k < 4; k++) hist[k*256 + tid] = 0;
    __syncthreads();

    const int e0 = blockIdx.x * 4096;
    int p0r[16], p1r[16];
#pragma unroll
    for(int k = 0; k < 16; k++){
      int e = e0 + k*256 + tid;
      if(e < E){
        int s = adj[e];
        int r = adj[e + E];
        float we = w[e];
        adj_out[e]     = (float)s;
        adj_out[e + E] = (float)r;
        int b = r >> 8;
        p0r[k] = s | ((r & 255) << 16) | (b << 24);
        p1r[k] = __float_as_int(we);
        atomicAdd(&hist[wv*256 + b], 1);
      }
    }
    __syncthreads();
    int h0 = hist[0*256+tid], h1 = hist[1*256+tid], h2 = hist[2*256+tid], h3 = hist[3*256+tid];
    int cb = h0 + h1 + h2 + h3;
    int lb = block_excl_scan(cb, tid, wsA);   // contains a sync
    lbase[tid]      = lb;
    wcur[0*256+tid] = lb;
    wcur[1*256+tid] = lb + h0;
    wcur[2*256+tid] = lb + h0 + h1;
    wcur[3*256+tid] = lb + h0 + h1 + h2;
    gbase[tid] = cb ? atomicAdd(&bucketSize[tid], cb) : 0;
    __syncthreads();
#pragma unroll
    for(int k = 0; k < 16; k++){
      int e = e0 + k*256 + tid;
      if(e < E){
        int b = ((unsigned)p0r[k]) >> 24;
        int pos = atomicAdd(&wcur[wv*256 + b], 1);
        stag[pos] = make_int2(p0r[k], p1r[k]);
      }
    }
    __syncthreads();
    int total = (e0 + 4096 <= E) ? 4096 : (E - e0);
    for(int i = tid; i < total; i += 256){
      int2 p = stag[i];
      int b = ((unsigned)p.x) >> 24;
      int loc = gbase[b] + (i - lbase[b]);
      if(loc < CAP) part[(size_t)b * CAP + loc] = p;
    }
    return;
  }

  // ---------------- stageA ----------------
  __bf16* Wh   = (__bf16*)smem;            // 32 KB
  float* hb_sh = (float*)(smem + 32768);   // 512 B
  float* y2_sh = (float*)(smem + 33280);   // 4 B

  for(int g = tid; g < 2048; g += 256){
    int nr = g >> 4, k16 = g & 15;
    const float* wp = W + nr * 128 + k16 * 8;
    float4 a = *(const float4*)wp;
    float4 b = *(const float4*)(wp + 4);
    bf16x8 h;
    h[0]=(__bf16)a.x; h[1]=(__bf16)a.y; h[2]=(__bf16)a.z; h[3]=(__bf16)a.w;
    h[4]=(__bf16)b.x; h[5]=(__bf16)b.y; h[6]=(__bf16)b.z; h[7]=(__bf16)b.w;
    *(bf16x8*)&Wh[nr * 128 + ((k16 ^ (nr & 15)) << 3)] = h;
  }
  if(tid < 64){
    int l = tid;
    float b0 = bias[l], b1 = bias[l + 64];
    float bn = fmaxf(sqrtf(wsum(b0*b0 + b1*b1)), MINN);
    float sb = tanhf(bn) / bn;
    float hb0 = sb*b0, hb1 = sb*b1;
    float hnn = fmaxf(sqrtf(wsum(hb0*hb0 + hb1*hb1)), MINN);
    if(hnn > MAXN){ float f = MAXN/hnn; hb0 *= f; hb1 *= f; }
    float y2 = wsum(hb0*hb0 + hb1*hb1);
    hb_sh[l] = hb0; hb_sh[l + 64] = hb1;
    if(l == 0) *y2_sh = y2;
  }
  __syncthreads();

  const int lane = tid & 63;
  const int wid  = tid >> 6;
  const int q    = lane >> 4;
  const int n15  = lane & 15;

  const int M0 = (blockIdx.x - nA) * 64 + wid * 16;
  if(M0 >= n) return;

  float hbv[8];
#pragma unroll
  for(int t = 0; t < 8; t++) hbv[t] = hb_sh[t*16 + n15];
  const float y2 = *y2_sh;

  floatx4 acc[8];
#pragma unroll
  for(int t = 0; t < 8; t++) acc[t] = (floatx4){0.f,0.f,0.f,0.f};

  float x2p = 0.f;
  int m = M0 + n15; if(m > n - 1) m = n - 1;
#pragma unroll
  for(int kk = 0; kk < 4; kk++){
    const float* xp = x + (size_t)m * 128 + kk * 32 + q * 8;
    float4 xa = *(const float4*)xp;
    float4 xb = *(const float4*)(xp + 4);
    x2p += xa.x*xa.x + xa.y*xa.y + xa.z*xa.z + xa.w*xa.w
         + xb.x*xb.x + xb.y*xb.y + xb.z*xb.z + xb.w*xb.w;
    bf16x8 a;
    a[0]=(__bf16)xa.x; a[1]=(__bf16)xa.y; a[2]=(__bf16)xa.z; a[3]=(__bf16)xa.w;
    a[4]=(__bf16)xb.x; a[5]=(__bf16)xb.y; a[6]=(__bf16)xb.z; a[7]=(__bf16)xb.w;
    int k16 = kk * 4 + q;
#pragma unroll
    for(int t = 0; t < 8; t++){
      bf16x8 b = *(bf16x8*)&Wh[(t*16 + n15) * 128 + ((k16 ^ n15) << 3)];
      acc[t] = __builtin_amdgcn_mfma_f32_16x16x32_bf16(a, b, acc[t], 0, 0, 0);
    }
  }
  x2p += __shfl_xor(x2p, 16);
  x2p += __shfl_xor(x2p, 32);

  float mp[4], dp[4];
#pragma unroll
  for(int i = 0; i < 4; i++){
    float mpi = 0.f, dpi = 0.f;
#pragma unroll
    for(int t = 0; t < 8; t++){ float v = acc[t][i]; mpi = fmaf(v, v, mpi); dpi = fmaf(v, hbv[t], dpi); }
    mpi += __shfl_xor(mpi, 1); mpi += __shfl_xor(mpi, 2); mpi += __shfl_xor(mpi, 4); mpi += __shfl_xor(mpi, 8);
    dpi += __shfl_xor(dpi, 1); dpi += __shfl_xor(dpi, 2); dpi += __shfl_xor(dpi, 4); dpi += __shfl_xor(dpi, 8);
    mp[i] = mpi; dp[i] = dpi;
  }

  const int li   = lane & 3;
  const int srcl = (((lane >> 2) << 4) | li) & 63;
  float selmp = li==0 ? mp[0] : li==1 ? mp[1] : li==2 ? mp[2] : mp[3];
  float seldp = li==0 ? dp[0] : li==1 ? dp[1] : li==2 ? dp[2] : dp[3];
  float tmp_mp = __shfl(selmp, srcl);
  float tmp_dp = __shfl(seldp, srcl);
  float mxn = fmaxf(sqrtf(tmp_mp), MINN);
  float xn  = fmaxf(sqrtf(x2p), MINN);
  float tt  = tanhf(mxn / xn * artanh_(xn));
  float s1  = tt / mxn;
  float rn  = fmaxf(tt, MINN);
  if(rn > MAXN) s1 *= MAXN / rn;
  float xy    = s1 * tmp_dp;
  float r2    = s1 * s1 * tmp_mp;
  float alpha = 1.f + 2.f*xy + y2;
  float beta  = 1.f - r2;
  float inv   = 1.f / fmaxf(1.f + 2.f*xy + r2*y2, MINN);
  float as1   = alpha * s1;

  float as1b[4], betab[4], invb[4];
#pragma unroll
  for(int i = 0; i < 4; i++){
    int sl = ((lane >> 4) << 2) | i;
    as1b[i]  = __shfl(as1, sl);
    betab[i] = __shfl(beta, sl);
    invb[i]  = __shfl(inv, sl);
  }

  float uv[4][8];
  float u2[4];
#pragma unroll
  for(int i = 0; i < 4; i++){
    float u2i = 0.f;
#pragma unroll
    for(int t = 0; t < 8; t++){
      float u = (as1b[i] * acc[t][i] + betab[i] * hbv[t]) * invb[i];
      uv[i][t] = u;
      u2i = fmaf(u, u, u2i);
    }
    u2i += __shfl_xor(u2i, 1); u2i += __shfl_xor(u2i, 2); u2i += __shfl_xor(u2i, 4); u2i += __shfl_xor(u2i, 8);
    u2[i] = u2i;
  }

  float selu = li==0 ? u2[0] : li==1 ? u2[1] : li==2 ? u2[2] : u2[3];
  float tu   = __shfl(selu, srcl);
  float un = fmaxf(sqrtf(tu), MINN);
  float sc = 1.f, hn = un;
  if(un > MAXN){ sc = MAXN/un; hn = MAXN; }
  float lt = artanh_(hn) / hn * sc;

#pragma unroll
  for(int i = 0; i < 4; i++){
    int grow = M0 + q * 4 + i;
    float lti = __shfl(lt, ((lane >> 4) << 2) | i);
    if(grow < n){
      halfx8 f;
#pragma unroll
      for(int t = 0; t < 8; t++) f[t] = (_Float16)(lti * uv[i][t]);
      *(halfx8*)(ht + (size_t)grow * 128 + n15 * 8) = f;
    }
  }
}

// ---------------- Pass B: per-bucket local CSR; writes offs + packed 4B epk ----------------
__global__ __launch_bounds__(256)
void passB_kernel(const int* __restrict__ bucketSize, const int2* __restrict__ part,
                  unsigned* __restrict__ epk, int* __restrict__ offs, int n)
{
  __shared__ int sizes[256];
  __shared__ int hist[256];
  __shared__ int cursor[256];
  __shared__ int wsA[4];
  __shared__ int2 stag[CAP];

  const int tid = threadIdx.x;
  const int b   = blockIdx.x;
  sizes[tid] = bucketSize[tid];
  hist[tid]  = 0;
  __syncthreads();
  int sb = block_excl_scan(sizes[tid], tid, wsA);   // contains a sync
  __shared__ int base_sh;
  if(tid == b) base_sh = sb;
  __syncthreads();
  const int base_b = base_sh;
  int size = sizes[b]; if(size > CAP) size = CAP;

  const int2* src = part + (size_t)b * CAP;
  for(int i = tid; i < size; i += 256){
    int2 p = src[i];
    stag[i] = p;
    atomicAdd(&hist[(((unsigned)p.x) >> 16) & 255], 1);
  }
  __syncthreads();
  int rb = block_excl_scan(hist[tid], tid, wsA);    // contains a sync
  int grow = b * 256 + tid;
  if(grow <= n) offs[grow] = base_b + rb;
  cursor[tid] = rb;
  __syncthreads();
  for(int i = tid; i < size; i += 256){
    int2 p = stag[i];
    int rlo = (((unsigned)p.x) >> 16) & 255;
    int pos = atomicAdd(&cursor[rlo], 1);
    unsigned wh = (unsigned)__builtin_bit_cast(unsigned short,
                    (_Float16)__builtin_bit_cast(float, p.y));
    epk[base_b + pos] = (unsigned)(p.x & 0xFFFF) | (wh << 16);
  }
}

// ---------------- fused aggregate + HypAct: 4 rows per wave (16 lanes/row) ----------------
__global__ __launch_bounds__(256)
void agg_act_kernel(const int* __restrict__ offs, const unsigned* __restrict__ epk,
                    const _Float16* __restrict__ ht, float* __restrict__ out, int n)
{
  __shared__ float tr[4][4][132];
  const int tid  = threadIdx.x;
  const int wid  = tid >> 6;
  const int lane = tid & 63;
  const int g = lane >> 4, i = lane & 15;
  const int row = blockIdx.x * 16 + wid * 4 + g;
  const char* htb = (const char*)ht;
  const int ioff = i << 4;

  half2_t acc2[4];
#pragma unroll
  for(int k = 0; k < 4; k++) acc2[k] = (half2_t){(_Float16)0.f, (_Float16)0.f};

#define EDGE(pk) { \
    int s_ = (int)((pk) & 0xFFFFu); \
    half2_t w2_ = __builtin_bit_cast(half2_t, __builtin_amdgcn_perm(pk, pk, 0x03020302u)); \
    int4 q_ = *(const int4*)(htb + ((s_ << 8) | ioff)); \
    acc2[0] = __builtin_bit_cast(half2_t, q_.x) * w2_ + acc2[0]; \
    acc2[1] = __builtin_bit_cast(half2_t, q_.y) * w2_ + acc2[1]; \
    acc2[2] = __builtin_bit_cast(half2_t, q_.z) * w2_ + acc2[2]; \
    acc2[3] = __builtin_bit_cast(half2_t, q_.w) * w2_ + acc2[3]; \
  }

  if(row < n){
    int beg = offs[row];
    int m   = offs[row + 1] - beg;
    const unsigned* ep = epk + beg;
    int t = 0;
    for(; t + 1 < m; t += 2){
      unsigned pk0 = ep[t];
      unsigned pk1 = ep[t + 1];
      EDGE(pk0);
      EDGE(pk1);
    }
    if(t < m) EDGE(ep[t]);
  }
#undef EDGE

  // epilogue: per-group (16-lane) — one chain serves 4 rows per wave
  float acc[8];
#pragma unroll
  for(int k = 0; k < 4; k++){
    acc[2*k]   = (float)acc2[k][0];
    acc[2*k+1] = (float)acc2[k][1];
  }
  float u2p = 0.f;
#pragma unroll
  for(int k = 0; k < 8; k++) u2p = fmaf(acc[k], acc[k], u2p);
  u2p += __shfl_xor(u2p, 1); u2p += __shfl_xor(u2p, 2);
  u2p += __shfl_xor(u2p, 4); u2p += __shfl_xor(u2p, 8);
  float un = fmaxf(sqrtf(u2p), MINN);
  float te = tanhf(un);
  float se = te / un;
  float gn = fmaxf(te, MINN);
  float hn = gn;
  if(gn > MAXN){ se *= MAXN/gn; hn = MAXN; }
  float la = artanh_(hn) / hn * se;
  float l[8];
  float r2p = 0.f;
#pragma unroll
  for(int k = 0; k < 8; k++){ l[k] = fmaxf(la*acc[k], 0.f); r2p = fmaf(l[k], l[k], r2p); }
  r2p += __shfl_xor(r2p, 1); r2p += __shfl_xor(r2p, 2);
  r2p += __shfl_xor(r2p, 4); r2p += __shfl_xor(r2p, 8);
  float rn = fmaxf(sqrtf(r2p), MINN);
  float t2 = tanhf(rn);
  float s2 = t2 / rn;
  float on = fmaxf(t2, MINN);
  if(on > MAXN) s2 *= MAXN/on;

  // un-permute via per-group LDS transpose: true dim of acc[k] is k*16+i
  if(row < n){
#pragma unroll
    for(int k = 0; k < 8; k++) tr[wid][g][k*16 + i] = s2 * l[k];
    float4 o0 = *(float4*)&tr[wid][g][i*8];
    float4 o1 = *(float4*)&tr[wid][g][i*8 + 4];
    float* orow = out + (size_t)row * 128 + i*8;
    *(float4*)orow       = o0;
    *(float4*)(orow + 4) = o1;
  }
}

extern "C" void kernel_launch(void* const* d_in, const int* in_sizes, int n_in,
                              void* d_out, int out_size, void* d_ws, size_t ws_size,
                              hipStream_t stream)
{
  const float* x    = (const float*)d_in[0];
  const int*   adj  = (const int*)  d_in[1];
  const float* w    = (const float*)d_in[2];
  const float* W    = (const float*)d_in[3];
  const float* bias = (const float*)d_in[4];
  const int n = in_sizes[0] / 128;   // 50000
  const int E = in_sizes[2];         // 800000

  float* out     = (float*)d_out;
  float* adj_out = out + (size_t)n * 128;

  char* ws = (char*)d_ws;
  _Float16* ht   = (_Float16*)ws;  ws += (size_t)n * 128 * sizeof(_Float16);   // 12.8 MB
  int2*  part    = (int2*)ws;      ws += (size_t)256 * CAP * sizeof(int2);     // 10.5 MB
  unsigned* epk  = (unsigned*)ws;  ws += (size_t)E * sizeof(unsigned);         // 3.2 MB
  int*   offs    = (int*)ws;       ws += (size_t)(n + 1) * sizeof(int);
  int*   bucketSize = (int*)ws;

  const int nA = (E + 4095) / 4096;   // 196 passA blocks
  const int nS = (n + 63) / 64;       // 782 stageA blocks

  hipMemsetAsync(bucketSize, 0, 256 * sizeof(int), stream);
  fusedA_kernel<<<nA + nS, 256, 0, stream>>>(x, W, bias, ht, n,
                                             adj, w, adj_out, bucketSize, part, E, nA);
  passB_kernel<<<(n + 255) / 256, 256, 0, stream>>>(bucketSize, part, epk, offs, n);
  agg_act_kernel<<<(n + 15) / 16, 256, 0, stream>>>(offs, epk, ht, out, n);
}